// Round 2
// baseline (3473.906 us; speedup 1.0000x reference)
//
#include <hip/hip_runtime.h>
#include <cstdint>
#include <cstddef>

// ---------------------------------------------------------------------------
// MambaFusion. R10 (on R9):
// - B-direct GEMMs: weight planes pre-swizzled into MFMA fragment order
//   ([n-frag][k-step][lane][8]); B fragments now load straight from L2 with
//   one coalesced dwordx4, no LDS staging / reads for B. 128^2 kernel LDS
//   halves (32->16KB); 64^2 kernel drops ~30% LDS traffic.
// - out_proj moved from 64^2 kernel to 128^2 kernel (grid 3x61, K=768);
//   ACT=4 combine epilogue added to mgemm_k.
// - NCHUNK 26->13 (TC=74): halves hchk traffic, p2 twice cheaper.
// Workspace: 57,981,952 floats = 232 MB (was 237.2).
// ---------------------------------------------------------------------------

constexpr int BZv = 16, SEQ = 5, NV = 1;
constexpr int C = 384, DSTATE = 16, DCONV = 4, NLAYER = 4;
constexpr int DI = 768;
constexpr int DTR = 24;
constexpr int NTOK = (NV + 2) * SEQ * 64;  // 960
constexpr int T = NTOK + 2;                // 962
constexpr int M = BZv * T;                 // 15392
constexpr int HB = 8;                      // batches per half
constexpr int MH = HB * T;                 // 7696 rows per half
constexpr int XZdim = 2 * DI;              // 1536
constexpr int ND = DTR + 2 * DSTATE;       // 56
constexpr int NDP = 32;                    // dt_r plane stride
constexpr int NCHUNK = 13, TC = 74;        // 13*74 == 962
constexpr int NQ = 241;                    // ceil(T/4) t-quads
constexpr size_t SEC_SZ = (size_t)BZv * SEQ * C * 64;

// swizzled weight set sizes (elements per (layer[,dir]) set)
constexpr size_t SET1 = (size_t)C * C;        // 147,456 (fc)
constexpr size_t SETI = (size_t)2 * DI * C;   // 589,824 (in_proj)
constexpr size_t SETO = (size_t)C * DI;       // 294,912 (out_proj)
constexpr size_t SETX = (size_t)64 * DI;      // 49,152  (x_proj, N padded 56->64)
constexpr size_t SETD = (size_t)DI * 32;      // 24,576  (dt_proj, K padded 24->32)
constexpr size_t WSZ1 = 4 * SET1;             // 589,824
constexpr size_t WSZI = 8 * SETI;             // 4,718,592
constexpr size_t WSZO = 8 * SETO;             // 2,359,296
constexpr size_t WSZX = 8 * SETX;             // 393,216
constexpr size_t WSZD = 8 * SETD;             // 196,608

typedef __attribute__((ext_vector_type(8))) short short8;
typedef __attribute__((ext_vector_type(4))) float floatx4;

#define GLOAD_LDS16(g, l)                                        \
  __builtin_amdgcn_global_load_lds(                              \
      (const __attribute__((address_space(1))) void*)(g),        \
      (__attribute__((address_space(3))) void*)(l), 16, 0, 0)

__device__ __forceinline__ void split_bf16(float v, short& hi, short& lo) {
  unsigned u = __float_as_uint(v);
  unsigned hib = u & 0xFFFF0000u;      // truncate to bf16
  float r = v - __uint_as_float(hib);  // exact residual
  hi = (short)(hib >> 16);
  lo = (short)(__float_as_uint(r) >> 16);
}

__device__ __forceinline__ float join_bf16(short h, short l) {
  return __uint_as_float((unsigned)(unsigned short)h << 16) +
         __uint_as_float((unsigned)(unsigned short)l << 16);
}

// e[s] = e1^(s+1), 15 muls, ~4 deep.
__device__ __forceinline__ void pow16(float e1, float* e) {
  e[0] = e1;
  e[1] = e1 * e1;
  e[3] = e[1] * e[1];
  e[7] = e[3] * e[3];
  e[15] = e[7] * e[7];
  e[2] = e[1] * e[0];
  e[4] = e[3] * e[0];
  e[5] = e[3] * e[1];
  e[6] = e[5] * e[0];
  e[8] = e[7] * e[0];
  e[9] = e[7] * e[1];
  e[10] = e[9] * e[0];
  e[11] = e[7] * e[3];
  e[12] = e[11] * e[0];
  e[13] = e[11] * e[1];
  e[14] = e[13] * e[0];
}

// ------------------------------ token assembly -----------------------------
// Blocks 0..719: (b, g_, cc) 64x128 tiles, LDS transpose, coalesced both
// ways, pe-add fused into the write pass. Block 720: gps tail rows.
__global__ __launch_bounds__(256) void assemble_t_k(
    const float* __restrict__ img, const float* __restrict__ lid,
    const float* __restrict__ rad, const float* __restrict__ gps,
    const float* __restrict__ pe, float* __restrict__ x) {
  __shared__ float lds[64][129];
  int blk = blockIdx.x, tid = threadIdx.x;
  if (blk < 720) {
    int b = blk / 45;
    int rem = blk % 45;
    int g_ = rem / 3, cc = rem % 3;
    int sec = g_ / 5, s = g_ % 5;
    int srow = b * 5 + s;
    int which = (cc + sec) % 3;
    const float* src = (which == 0) ? img : (which == 1 ? lid : rad);
    const float* sp = src + (size_t)srow * (C * 64) + cc * 8192;
#pragma unroll
    for (int i = 0; i < 32; i++) {
      int lin = tid + 256 * i;
      lds[lin & 63][lin >> 6] = sp[lin];
    }
    __syncthreads();
#pragma unroll
    for (int i = 0; i < 32; i++) {
      int lin = tid + 256 * i;
      int p = lin >> 7, c = lin & 127;
      int t = g_ * 64 + p;
      int ccc = cc * 128 + c;
      x[((size_t)b * T + t) * C + ccc] = lds[p][c] + pe[(size_t)t * C + ccc];
    }
  } else {
#pragma unroll
    for (int i = 0; i < 48; i++) {
      int lin = tid + 256 * i;
      int r = lin / C, c = lin % C;
      int b = r >> 1, e = r & 1;
      x[((size_t)b * T + NTOK + e) * C + c] =
          gps[((size_t)b * 2 + e) * C + c] + pe[(size_t)(NTOK + e) * C + c];
    }
  }
}

// -------------------- fused LN (stats + apply -> planes) -------------------
__global__ __launch_bounds__(256) void ln_fused_k(
    const float* __restrict__ x, const float* __restrict__ g,
    const float* __restrict__ b, short* __restrict__ oh,
    short* __restrict__ ol) {
  int row = blockIdx.x * 4 + (threadIdx.x >> 6);
  int lane = threadIdx.x & 63;
  const float* xr = x + (size_t)row * C;
  float v[6];
  float s = 0.f;
#pragma unroll
  for (int j = 0; j < 6; j++) {
    v[j] = xr[lane + 64 * j];
    s += v[j];
  }
#pragma unroll
  for (int o = 32; o > 0; o >>= 1) s += __shfl_xor(s, o, 64);
  float mean = s * (1.f / 384.f);
  float q = 0.f;
#pragma unroll
  for (int j = 0; j < 6; j++) {
    float d = v[j] - mean;
    q += d * d;
  }
#pragma unroll
  for (int o = 32; o > 0; o >>= 1) q += __shfl_xor(q, o, 64);
  float rstd = rsqrtf(q * (1.f / 384.f) + 1e-5f);
#pragma unroll
  for (int j = 0; j < 6; j++) {
    int c = lane + 64 * j;
    float val = (v[j] - mean) * rstd * g[c] + b[c];
    short h, l;
    split_bf16(val, h, l);
    oh[(size_t)row * C + c] = h;
    ol[(size_t)row * C + c] = l;
  }
}

// ------------------------- LN row stats (final LN) -------------------------
__global__ __launch_bounds__(256) void ln_stats2_k(const float* __restrict__ x,
                                                   float* __restrict__ stats) {
  int row = blockIdx.x * 4 + (threadIdx.x >> 6);
  int lane = threadIdx.x & 63;
  const float* xr = x + (size_t)row * C;
  float v[6];
  float s = 0.f;
#pragma unroll
  for (int j = 0; j < 6; j++) {
    v[j] = xr[lane + 64 * j];
    s += v[j];
  }
#pragma unroll
  for (int o = 32; o > 0; o >>= 1) s += __shfl_xor(s, o, 64);
  float mean = s * (1.f / 384.f);
  float q = 0.f;
#pragma unroll
  for (int j = 0; j < 6; j++) {
    float d = v[j] - mean;
    q += d * d;
  }
#pragma unroll
  for (int o = 32; o > 0; o >>= 1) q += __shfl_xor(q, o, 64);
  if (lane == 0) {
    stats[2 * row] = mean;
    stats[2 * row + 1] = rsqrtf(q * (1.f / 384.f) + 1e-5f);
  }
}

// ------------------ weight cast to swizzled fragment order -----------------
// Output layout per set: idx = ((nf*KS + ks)*64 + lane)*8 + e, holding
// W[n = nf*16 + (lane&15)][k = ks*32 + (lane>>4)*8 + e], zero-padded when
// n >= NSRC or k >= KSRC. grid: (NP*KS*32/256, nsets).
template <int NSRC, int KSRC, int KS>
__global__ __launch_bounds__(256) void cast_swz_k(const float* __restrict__ src,
                                                  short* __restrict__ oh,
                                                  short* __restrict__ ol) {
  constexpr int NP = (NSRC + 15) & ~15;
  constexpr size_t SETSZ = (size_t)NP * KS * 32;
  int set = blockIdx.y;
  size_t idx = (size_t)blockIdx.x * 256 + threadIdx.x;
  int e = (int)(idx & 7);
  int lane = (int)((idx >> 3) & 63);
  size_t rest = idx >> 9;
  int ks = (int)(rest % KS);
  int nf = (int)(rest / KS);
  int n = nf * 16 + (lane & 15);
  int k = ks * 32 + ((lane >> 4) << 3) + e;
  float v = 0.f;
  if (n < NSRC && k < KSRC)
    v = src[(size_t)set * NSRC * KSRC + (size_t)n * KSRC + k];
  short h, l;
  split_bf16(v, h, l);
  oh[(size_t)set * SETSZ + idx] = h;
  ol[(size_t)set * SETSZ + idx] = l;
}

// ------------------ split-bf16 MFMA GEMM (128x128, B-direct) ---------------
// ACT: 0 none, 1 lrelu(0.2), 4 combine v = e2*(e1 + v).
// OSPLIT: write hi/lo planes (stride N). W in swizzled fragment order.
template <int ACT, bool BIAS, bool FLIPA, bool OSPLIT>
__global__ __launch_bounds__(256) void mgemm_k(
    const short* __restrict__ Ah, const short* __restrict__ Al, int K,
    const short* __restrict__ Wh, const short* __restrict__ Wl, int N,
    const float* __restrict__ bias, float* __restrict__ Co, int ldc,
    short* __restrict__ Oh, short* __restrict__ Ol,
    const float* __restrict__ e1, const float* __restrict__ e2, int Mrows,
    int arow_off, int crow_off) {
  __shared__ __align__(16) short sAh[128 * 32];
  __shared__ __align__(16) short sAl[128 * 32];
  const int tid = threadIdx.x;
  const int wave = tid >> 6, lane = tid & 63;
  const int m0 = blockIdx.y * 128, n0 = blockIdx.x * 128;
  const int lrow = lane >> 2, lchunk = lane & 3;
  const int wm = (wave >> 1) * 64, wn = (wave & 1) * 64;
  const int frow = lane & 15, fquad = lane >> 4;
  const int KST = K >> 5;
  const int nfb = (n0 + wn) >> 4;

  size_t arow[2];
#pragma unroll
  for (int p = 0; p < 2; p++) {
    int r = p * 64 + wave * 16 + lrow;
    int lm = m0 + r;
    if (lm >= Mrows) lm = Mrows - 1;
    int g = arow_off + lm;
    if (FLIPA) {
      int bb = g / T;
      int tt = g - bb * T;
      g = bb * T + (T - 1 - tt);
    }
    arow[p] = (size_t)g * K;
  }

  floatx4 acc[4][4] = {};
  for (int k0 = 0; k0 < K; k0 += 32) {
    if (k0) __syncthreads();
    const int kc = k0 + lchunk * 8;
#pragma unroll
    for (int p = 0; p < 2; p++) {
      GLOAD_LDS16(Ah + arow[p] + kc, &sAh[(p * 64 + wave * 16) * 32]);
      GLOAD_LDS16(Al + arow[p] + kc, &sAl[(p * 64 + wave * 16) * 32]);
    }
    const int ks = k0 >> 5;
    short8 bh[4], bl[4];
#pragma unroll
    for (int j = 0; j < 4; j++) {
      size_t bo = (((size_t)(nfb + j) * KST + ks) * 64 + lane) * 8;
      bh[j] = *(const short8*)&Wh[bo];
      bl[j] = *(const short8*)&Wl[bo];
    }
    __syncthreads();
    short8 ah[4], al[4];
#pragma unroll
    for (int i = 0; i < 4; i++) {
      int ra = (wm + i * 16 + frow) * 32 + fquad * 8;
      ah[i] = *(const short8*)&sAh[ra];
      al[i] = *(const short8*)&sAl[ra];
    }
#pragma unroll
    for (int i = 0; i < 4; i++)
#pragma unroll
      for (int j = 0; j < 4; j++) {
        acc[i][j] = __builtin_amdgcn_mfma_f32_16x16x32_bf16(ah[i], bh[j],
                                                            acc[i][j], 0, 0, 0);
        acc[i][j] = __builtin_amdgcn_mfma_f32_16x16x32_bf16(al[i], bh[j],
                                                            acc[i][j], 0, 0, 0);
        acc[i][j] = __builtin_amdgcn_mfma_f32_16x16x32_bf16(ah[i], bl[j],
                                                            acc[i][j], 0, 0, 0);
      }
  }
#pragma unroll
  for (int i = 0; i < 4; i++) {
#pragma unroll
    for (int r = 0; r < 4; r++) {
      int gm = m0 + wm + i * 16 + fquad * 4 + r;
      if (gm >= Mrows) continue;
      int grow = crow_off + gm;
#pragma unroll
      for (int j = 0; j < 4; j++) {
        int gn = n0 + wn + j * 16 + frow;
        if (gn >= N) continue;
        float v = acc[i][j][r];
        if constexpr (BIAS) v += bias[gn];
        if constexpr (ACT == 1) v = v >= 0.f ? v : 0.2f * v;
        if constexpr (ACT == 4) {
          size_t o = (size_t)grow * ldc + gn;
          v = e2[o] * (e1[o] + v);
        }
        if constexpr (OSPLIT) {
          short h, l;
          split_bf16(v, h, l);
          Oh[(size_t)grow * N + gn] = h;
          Ol[(size_t)grow * N + gn] = l;
        } else {
          Co[(size_t)grow * ldc + gn] = v;
        }
      }
    }
  }
}

// ------------------- split-bf16 MFMA GEMM (64x64, B-direct) ----------------
// OMODE: 0 fp32 Co (stride ldc), 2 x_proj dual: planes (stride NDP) for
//        gn<32 AND fp32 Co[row*32 + gn-24] for gn>=24 (B/C region).
// ACT: 0 none, 2 fast-softplus.
template <int ACT, bool BIAS, int OMODE>
__global__ __launch_bounds__(256) void mgemm64_k(
    const short* __restrict__ Ah, const short* __restrict__ Al, int lda, int K,
    const short* __restrict__ Wh, const short* __restrict__ Wl, int N,
    const float* __restrict__ bias, float* __restrict__ Co, int ldc,
    short* __restrict__ Oh, short* __restrict__ Ol, int Mrows, int crow_off) {
  __shared__ __align__(16) short sAh[64 * 32];
  __shared__ __align__(16) short sAl[64 * 32];
  const int tid = threadIdx.x;
  const int wave = tid >> 6, lane = tid & 63;
  const int m0 = blockIdx.y * 64, n0 = blockIdx.x * 64;
  const int schunk = tid & 3;
  const int frow = lane & 15, fquad = lane >> 4;
  const int KST = K >> 5;
  const int nfw = (n0 >> 4) + wave;

  int lm = m0 + (tid >> 2);
  if (lm >= Mrows) lm = Mrows - 1;
  size_t aoff = (size_t)lm * lda;

  floatx4 acc[4] = {};
  for (int k0 = 0; k0 < K; k0 += 32) {
    if (k0) __syncthreads();
    const int kc = k0 + schunk * 8;
    GLOAD_LDS16(Ah + aoff + kc, &sAh[(wave * 16) * 32]);
    GLOAD_LDS16(Al + aoff + kc, &sAl[(wave * 16) * 32]);
    const int ks = k0 >> 5;
    short8 bh, bl;
    {
      size_t bo = (((size_t)nfw * KST + ks) * 64 + lane) * 8;
      bh = *(const short8*)&Wh[bo];
      bl = *(const short8*)&Wl[bo];
    }
    __syncthreads();
    short8 ah[4], al[4];
#pragma unroll
    for (int i = 0; i < 4; i++) {
      int ra = (i * 16 + frow) * 32 + fquad * 8;
      ah[i] = *(const short8*)&sAh[ra];
      al[i] = *(const short8*)&sAl[ra];
    }
#pragma unroll
    for (int i = 0; i < 4; i++) {
      acc[i] = __builtin_amdgcn_mfma_f32_16x16x32_bf16(ah[i], bh, acc[i], 0, 0, 0);
      acc[i] = __builtin_amdgcn_mfma_f32_16x16x32_bf16(al[i], bh, acc[i], 0, 0, 0);
      acc[i] = __builtin_amdgcn_mfma_f32_16x16x32_bf16(ah[i], bl, acc[i], 0, 0, 0);
    }
  }
  const int gn = n0 + wave * 16 + frow;
  if (gn < N) {
#pragma unroll
    for (int i = 0; i < 4; i++) {
#pragma unroll
      for (int r = 0; r < 4; r++) {
        int gm = m0 + i * 16 + fquad * 4 + r;
        if (gm >= Mrows) continue;
        int grow = crow_off + gm;
        float v = acc[i][r];
        if constexpr (BIAS) v += bias[gn];
        if constexpr (ACT == 2) v = (v > 20.f) ? v : __logf(1.f + __expf(v));
        if constexpr (OMODE == 2) {
          if (gn < NDP) {
            short h, l;
            split_bf16(v, h, l);
            Oh[(size_t)grow * NDP + gn] = h;
            Ol[(size_t)grow * NDP + gn] = l;
          }
          if (gn >= DTR) Co[(size_t)grow * 32 + (gn - DTR)] = v;
        } else {
          Co[(size_t)grow * ldc + gn] = v;
        }
      }
    }
  }
}

// --------------------------- depthwise conv + silu -------------------------
__global__ __launch_bounds__(256) void conv_k(const float* __restrict__ xz,
                                              const float* __restrict__ cw,
                                              const float* __restrict__ cb,
                                              short* __restrict__ xch,
                                              short* __restrict__ xcl) {
  int idx = blockIdx.x * 256 + threadIdx.x;  // [0, HB*NQ*384)
  int dh = idx % (DI / 2);
  int rem = idx / (DI / 2);
  int q = rem % NQ;
  int b = rem / NQ;
  int d = dh * 2;
  int t0 = q * 4;
  const float* base = xz + (size_t)b * T * XZdim + d;
  float4 cwa = *(const float4*)&cw[d * 4];
  float4 cwb = *(const float4*)&cw[(d + 1) * 4];
  float cb0 = cb[d], cb1 = cb[d + 1];
  float2 w[7];
#pragma unroll
  for (int j = 0; j < 7; j++) {
    int tt = t0 - 3 + j;
    w[j] = (tt >= 0 && tt < T) ? *(const float2*)(base + (size_t)tt * XZdim)
                               : make_float2(0.f, 0.f);
  }
  const float cwx[4] = {cwa.x, cwa.y, cwa.z, cwa.w};
  const float cwy[4] = {cwb.x, cwb.y, cwb.z, cwb.w};
#pragma unroll
  for (int r = 0; r < 4; r++) {
    int t = t0 + r;
    if (t >= T) break;
    float a0 = cb0, a1 = cb1;
#pragma unroll
    for (int j = 0; j < 4; j++) {
      a0 += w[r + j].x * cwx[j];
      a1 += w[r + j].y * cwy[j];
    }
    float v0 = a0 / (1.f + __expf(-a0));
    float v1 = a1 / (1.f + __expf(-a1));
    short h0, l0, h1, l1;
    split_bf16(v0, h0, l0);
    split_bf16(v1, h1, l1);
    size_t o = ((size_t)b * T + t) * DI + d;
    *(short2*)&xch[o] = make_short2(h0, h1);
    *(short2*)&xcl[o] = make_short2(l0, l1);
  }
}

// ----------------------- chunked selective scan ----------------------------
// Phase 1: local scan from h=0; stores h_local[16] + sum(dt) per (b,ch,d).
__global__ __launch_bounds__(256) void scan_p1_k(
    const float* __restrict__ xzb, const short* __restrict__ xch,
    const short* __restrict__ xcl, const float* __restrict__ xdbc,
    const float* __restrict__ alog, float* __restrict__ hchk,
    float* __restrict__ sdt) {
  int d = blockIdx.x * 256 + threadIdx.x;
  int ch = blockIdx.y, b = blockIdx.z;
  float A[DSTATE], h[DSTATE];
  bool powA = true;
#pragma unroll
  for (int s = 0; s < DSTATE; s++) {
    A[s] = -expf(alog[d * DSTATE + s]);
    powA = powA && (fabsf(A[s] + (float)(s + 1)) <= 1e-4f * (float)(s + 1));
    h[s] = 0.f;
  }
  const int t0 = ch * TC;
  const float* xzr = xzb + ((size_t)b * T + t0) * XZdim;
  const short* xchr = xch + ((size_t)b * T + t0) * DI;
  const short* xclr = xcl + ((size_t)b * T + t0) * DI;
  const float* bcr = xdbc + ((size_t)b * T + t0) * 32;
  float sd = 0.f;
  if (powA) {
    for (int t = 0; t < TC; t++) {
      float dt = xzr[(size_t)t * XZdim + d];
      float xv = join_bf16(xchr[(size_t)t * DI + d], xclr[(size_t)t * DI + d]);
      float dx = dt * xv;
      const float* bc = bcr + (size_t)t * 32;
      sd += dt;
      float ev[DSTATE];
      pow16(__expf(-dt), ev);
#pragma unroll
      for (int s = 0; s < DSTATE; s++) h[s] = h[s] * ev[s] + dx * bc[s];
    }
  } else {
    for (int t = 0; t < TC; t++) {
      float dt = xzr[(size_t)t * XZdim + d];
      float xv = join_bf16(xchr[(size_t)t * DI + d], xclr[(size_t)t * DI + d]);
      float dx = dt * xv;
      const float* bc = bcr + (size_t)t * 32;
      sd += dt;
#pragma unroll
      for (int s = 0; s < DSTATE; s++)
        h[s] = h[s] * __expf(dt * A[s]) + dx * bc[s];
    }
  }
  size_t o = ((size_t)(b * NCHUNK + ch) * DSTATE) * DI + d;
#pragma unroll
  for (int s = 0; s < DSTATE; s++) hchk[o + (size_t)s * DI] = h[s];
  sdt[(size_t)(b * NCHUNK + ch) * DI + d] = sd;
}

// Phase 2: per (b,s,d), NCHUNK-chunk recurrence; P recomputed from sdt.
__global__ __launch_bounds__(256) void scan_p2_k(float* __restrict__ hchk,
                                                 const float* __restrict__ sdt,
                                                 const float* __restrict__ alog) {
  int idx = blockIdx.x * 256 + threadIdx.x;  // [0, HB*DSTATE*DI)
  int d = idx % DI;
  int rem = idx / DI;
  int s = rem % DSTATE, b = rem / DSTATE;
  float A = -expf(alog[d * DSTATE + s]);
  float hin = 0.f;
#pragma unroll
  for (int ch = 0; ch < NCHUNK; ch++) {
    size_t o = ((size_t)(b * NCHUNK + ch) * DSTATE + s) * DI + d;
    float P = __expf(A * sdt[(size_t)(b * NCHUNK + ch) * DI + d]);
    float hl = hchk[o];
    hchk[o] = hin;
    hin = P * hin + hl;
  }
}

// Phase 3: rescan from incoming state; y = h.C + D*x, gated silu(z) -> planes.
__global__ __launch_bounds__(256) void scan_p3_k(
    const float* __restrict__ xzb, const short* __restrict__ xch,
    const short* __restrict__ xcl, const float* __restrict__ xdbc,
    const float* __restrict__ alog, const float* __restrict__ Dp,
    const float* __restrict__ hchk, short* __restrict__ yh,
    short* __restrict__ yl) {
  int d = blockIdx.x * 256 + threadIdx.x;
  int ch = blockIdx.y, b = blockIdx.z;
  float A[DSTATE], h[DSTATE];
  bool powA = true;
  size_t o = ((size_t)(b * NCHUNK + ch) * DSTATE) * DI + d;
#pragma unroll
  for (int s = 0; s < DSTATE; s++) {
    A[s] = -expf(alog[d * DSTATE + s]);
    powA = powA && (fabsf(A[s] + (float)(s + 1)) <= 1e-4f * (float)(s + 1));
    h[s] = hchk[o + (size_t)s * DI];
  }
  float Dd = Dp[d];
  const int t0 = ch * TC;
  const float* xzr = xzb + ((size_t)b * T + t0) * XZdim;
  const short* xchr = xch + ((size_t)b * T + t0) * DI;
  const short* xclr = xcl + ((size_t)b * T + t0) * DI;
  const float* bcr = xdbc + ((size_t)b * T + t0) * 32;
  if (powA) {
    for (int t = 0; t < TC; t++) {
      float dt = xzr[(size_t)t * XZdim + d];
      float xv = join_bf16(xchr[(size_t)t * DI + d], xclr[(size_t)t * DI + d]);
      float zv = xzr[(size_t)t * XZdim + DI + d];
      float dx = dt * xv;
      float accv = 0.f;
      const float* bc = bcr + (size_t)t * 32;
      float ev[DSTATE];
      pow16(__expf(-dt), ev);
#pragma unroll
      for (int s = 0; s < DSTATE; s++) {
        h[s] = h[s] * ev[s] + dx * bc[s];
        accv += h[s] * bc[DSTATE + s];
      }
      float y = accv + Dd * xv;
      float sz = zv / (1.f + __expf(-zv));
      float v = y * sz;
      short hh, ll;
      split_bf16(v, hh, ll);
      size_t oi = ((size_t)(b * T + t0 + t)) * DI + d;
      yh[oi] = hh;
      yl[oi] = ll;
    }
  } else {
    for (int t = 0; t < TC; t++) {
      float dt = xzr[(size_t)t * XZdim + d];
      float xv = join_bf16(xchr[(size_t)t * DI + d], xclr[(size_t)t * DI + d]);
      float zv = xzr[(size_t)t * XZdim + DI + d];
      float dx = dt * xv;
      float accv = 0.f;
      const float* bc = bcr + (size_t)t * 32;
#pragma unroll
      for (int s = 0; s < DSTATE; s++) {
        h[s] = h[s] * __expf(dt * A[s]) + dx * bc[s];
        accv += h[s] * bc[DSTATE + s];
      }
      float y = accv + Dd * xv;
      float sz = zv / (1.f + __expf(-zv));
      float v = y * sz;
      short hh, ll;
      split_bf16(v, hh, ll);
      size_t oi = ((size_t)(b * T + t0 + t)) * DI + d;
      yh[oi] = hh;
      yl[oi] = ll;
    }
  }
}

// ---------------- final LN + transpose scatter (contiguous writes) ---------
__global__ __launch_bounds__(256) void ln_scatter_k(
    const float* __restrict__ x, const float* __restrict__ stats,
    const float* __restrict__ g, const float* __restrict__ bb,
    float* __restrict__ out) {
  __shared__ float lds[64][129];
  int blk = blockIdx.x, tid = threadIdx.x;
  if (blk < 240) {
    int b = blk / 15, g_ = blk % 15;
    int sec = g_ / 5, s = g_ % 5;
    const int rbase = b * T + g_ * 64;
    for (int cc = 0; cc < 3; cc++) {
      if (cc) __syncthreads();
#pragma unroll
      for (int i = 0; i < 32; i++) {
        int lin = tid + 256 * i;  // [0, 8192)
        int p = lin >> 7, c = lin & 127;
        int row = rbase + p;
        int ccc = cc * 128 + c;
        float v = x[(size_t)row * C + ccc];
        v = (v - stats[2 * row]) * stats[2 * row + 1] * g[ccc] + bb[ccc];
        lds[p][c] = v;
      }
      __syncthreads();
      size_t obase = (size_t)sec * SEC_SZ +
                     (((size_t)(b * 5 + s) * C + cc * 128) << 6);
#pragma unroll
      for (int i = 0; i < 32; i++) {
        int lin = tid + 256 * i;
        int c = lin >> 6, p = lin & 63;
        out[obase + ((size_t)c << 6) + p] = lds[p][c];
      }
    }
  } else {
#pragma unroll
    for (int i = 0; i < 48; i++) {
      int lin = tid + 256 * i;
      int r = lin / C, c = lin % C;
      int b = r >> 1, e = r & 1;
      int row = b * T + NTOK + e;
      float v = x[(size_t)row * C + c];
      v = (v - stats[2 * row]) * stats[2 * row + 1] * g[c] + bb[c];
      out[3 * SEC_SZ + ((size_t)(b * 2 + e)) * C + c] = v;
    }
  }
}

// --------------------------------- launch ----------------------------------
extern "C" void kernel_launch(void* const* d_in, const int* in_sizes, int n_in,
                              void* d_out, int out_size, void* d_ws,
                              size_t ws_size, hipStream_t stream) {
  const float* image = (const float*)d_in[0];
  const float* lidar = (const float*)d_in[1];
  const float* radar = (const float*)d_in[2];
  const float* gps = (const float*)d_in[3];
  const float* pe = (const float*)d_in[4];
  const float* ln1g = (const float*)d_in[5];
  const float* ln1b = (const float*)d_in[6];
  const float* fc1w = (const float*)d_in[7];
  const float* fc1b = (const float*)d_in[8];
  const float* fc2w = (const float*)d_in[9];
  const float* fc2b_ = (const float*)d_in[10];
  const float* inw = (const float*)d_in[11];
  const float* cw = (const float*)d_in[12];
  const float* cb = (const float*)d_in[13];
  const float* xw = (const float*)d_in[14];
  const float* dtw = (const float*)d_in[15];
  const float* dtb = (const float*)d_in[16];
  const float* alog = (const float*)d_in[17];
  const float* Dp = (const float*)d_in[18];
  const float* ow = (const float*)d_in[19];
  const float* lnfg = (const float*)d_in[20];
  const float* lnfb = (const float*)d_in[21];
  float* out = (float*)d_out;

  // ---------------- workspace carve-up (57,981,952 floats = 232 MB) --------
  constexpr size_t MC = (size_t)M * C;  // 5,910,528
  float* ws = (float*)d_ws;
  float* x = ws;                            // MC
  float* fcb = x + MC;                      // MC (fc2 lrelu result)
  float* bmfm = fcb + MC;                   // MC (ln planes alias; then bm)
  float* x1f = bmfm + MC;                   // MC (x1 planes)
  float* yf = x1f + MC;                     // MC (y planes, half-local)
  float* xz_h = yf + MC;                    // MH*1536
  float* xcp = xz_h + (size_t)MH * XZdim;   // MH*DI floats (xc planes)
  float* xdp = xcp + (size_t)MH * DI;       // MH*64 floats (dt planes + B/C)
  constexpr size_t CHK_H = (size_t)HB * NCHUNK * DSTATE * DI;  // 1,277,952
  float* hchk = xdp + (size_t)MH * 64;
  float* sdtb = hchk + CHK_H;               // HB*NCHUNK*DI = 79,872
  float* wpl = sdtb + (size_t)HB * NCHUNK * DI;
  float* stats2 = hchk;  // final-LN stats alias (hchk dead by then)

  short* lnh = (short*)bmfm;  // ln planes dead before bm written
  short* lnl = lnh + MC;
  float* bm = bmfm;  // dir1 out_proj result (fp32, full M)
  short* x1h = (short*)x1f;
  short* x1l = x1h + MC;
  short* yh = (short*)yf;
  short* yl = yh + (size_t)MH * DI;
  short* xch = (short*)xcp;
  short* xcl = xch + (size_t)MH * DI;
  short* xdh = (short*)xdp;                  // MH*32 shorts (dt_r hi plane)
  short* xdl = xdh + (size_t)MH * NDP;       // MH*32 shorts (dt_r lo plane)
  float* xdbc = xdp + (size_t)MH * 32;       // MH*32 floats (fp32 B|C)

  short* wf1h = (short*)wpl;
  short* wf1l = wf1h + WSZ1;
  short* wf2h = wf1l + WSZ1;
  short* wf2l = wf2h + WSZ1;
  short* winh = wf2l + WSZ1;
  short* winl = winh + WSZI;
  short* wowh = winl + WSZI;
  short* wowl = wowh + WSZO;
  short* wxh = wowl + WSZO;
  short* wxl = wxh + WSZX;
  short* wdth = wxl + WSZX;
  short* wdtl = wdth + WSZD;

  // ------------- weight casts to swizzled fragment order (per call) --------
  cast_swz_k<C, C, 12><<<dim3((int)(SET1 / 256), 4), 256, 0, stream>>>(
      fc1w, wf1h, wf1l);
  cast_swz_k<C, C, 12><<<dim3((int)(SET1 / 256), 4), 256, 0, stream>>>(
      fc2w, wf2h, wf2l);
  cast_swz_k<2 * DI, C, 12><<<dim3((int)(SETI / 256), 8), 256, 0, stream>>>(
      inw, winh, winl);
  cast_swz_k<C, DI, 24><<<dim3((int)(SETO / 256), 8), 256, 0, stream>>>(
      ow, wowh, wowl);
  cast_swz_k<ND, DI, 24><<<dim3((int)(SETX / 256), 8), 256, 0, stream>>>(
      xw, wxh, wxl);
  cast_swz_k<DI, DTR, 1><<<dim3((int)(SETD / 256), 8), 256, 0, stream>>>(
      dtw, wdth, wdtl);

  assemble_t_k<<<721, 256, 0, stream>>>(image, lidar, radar, gps, pe, x);

  for (int l = 0; l < NLAYER; l++) {
    ln_fused_k<<<M / 4, 256, 0, stream>>>(x, ln1g + l * C, ln1b + l * C, lnh,
                                          lnl);
    // fc1 = LN(x) @ fc1_w^T + b -> bf16 planes (full M)
    mgemm_k<0, true, false, true><<<dim3(3, 121), 256, 0, stream>>>(
        lnh, lnl, C, wf1h + l * SET1, wf1l + l * SET1, C, fc1b + l * C,
        nullptr, 0, x1h, x1l, nullptr, nullptr, M, 0, 0);
    // fcb = lrelu(flip(xfc1) @ fc2_w^T + b) -> fp32 (full M)
    mgemm_k<1, true, true, false><<<dim3(3, 121), 256, 0, stream>>>(
        x1h, x1l, C, wf2h + l * SET1, wf2l + l * SET1, C, fc2b_ + l * C, fcb,
        C, nullptr, nullptr, nullptr, nullptr, M, 0, 0);
    // dir1 (backward) first -> bm; dir0 last fuses combine into x.
    for (int di = 0; di < 2; di++) {
      const int dir = 1 - di;
      size_t wo = (size_t)(l * 2 + dir);
      for (int h = 0; h < 2; h++) {
        const int roff = h * MH;
        // in_proj -> xz_h (dir1 reads time-flipped rows of x1)
        if (dir == 0)
          mgemm_k<0, false, false, false><<<dim3(12, 61), 256, 0, stream>>>(
              x1h, x1l, C, winh + wo * SETI, winl + wo * SETI, 2 * DI, nullptr,
              xz_h, XZdim, nullptr, nullptr, nullptr, nullptr, MH, roff, 0);
        else
          mgemm_k<0, false, true, false><<<dim3(12, 61), 256, 0, stream>>>(
              x1h, x1l, C, winh + wo * SETI, winl + wo * SETI, 2 * DI, nullptr,
              xz_h, XZdim, nullptr, nullptr, nullptr, nullptr, MH, roff, 0);
        // causal depthwise conv + silu -> xc planes (4-t quad)
        conv_k<<<(HB * NQ * (DI / 2)) / 256, 256, 0, stream>>>(
            xz_h, cw + wo * DI * DCONV, cb + wo * DI, xch, xcl);
        // x_proj -> dt_r planes (stride 32) + fp32 B/C (xdbc)
        mgemm64_k<0, false, 2><<<dim3(1, 121), 256, 0, stream>>>(
            xch, xcl, DI, DI, wxh + wo * SETX, wxl + wo * SETX, ND, nullptr,
            xdbc, 0, xdh, xdl, MH, 0);
        // dt_proj (K padded 24->32, zero weight pad) + fast softplus -> xz dt
        mgemm64_k<2, true, 0><<<dim3(12, 121), 256, 0, stream>>>(
            xdh, xdl, NDP, 32, wdth + wo * SETD, wdtl + wo * SETD, DI,
            dtb + wo * DI, xz_h, XZdim, nullptr, nullptr, MH, 0);
        // chunked selective scan -> y planes
        scan_p1_k<<<dim3(3, NCHUNK, HB), 256, 0, stream>>>(
            xz_h, xch, xcl, xdbc, alog + wo * DI * DSTATE, hchk, sdtb);
        scan_p2_k<<<(HB * DSTATE * DI) / 256, 256, 0, stream>>>(
            hchk, sdtb, alog + wo * DI * DSTATE);
        scan_p3_k<<<dim3(3, NCHUNK, HB), 256, 0, stream>>>(
            xz_h, xch, xcl, xdbc, alog + wo * DI * DSTATE, Dp + wo * DI, hchk,
            yh, yl);
        // out_proj (128^2): dir1 -> bm (plain); dir0 -> x = bm*(fcb + v)
        if (dir == 1)
          mgemm_k<0, false, false, false><<<dim3(3, 61), 256, 0, stream>>>(
              yh, yl, DI, wowh + wo * SETO, wowl + wo * SETO, C, nullptr, bm,
              C, nullptr, nullptr, nullptr, nullptr, MH, 0, roff);
        else
          mgemm_k<4, false, false, false><<<dim3(3, 61), 256, 0, stream>>>(
              yh, yl, DI, wowh + wo * SETO, wowl + wo * SETO, C, nullptr, x, C,
              nullptr, nullptr, fcb, bm, MH, 0, roff);
      }
    }
  }
  ln_stats2_k<<<M / 4, 256, 0, stream>>>(x, stats2);
  ln_scatter_k<<<241, 256, 0, stream>>>(x, stats2, lnfg, lnfb, out);
}

// Round 3
// 3344.834 us; speedup vs baseline: 1.0386x; 1.0386x over previous
//
#include <hip/hip_runtime.h>
#include <cstdint>
#include <cstddef>

// ---------------------------------------------------------------------------
// MambaFusion. R11 (on R10):
// R10 post-mortem: the +383us regression was out_proj moved to the 128^2
// kernel -> grid (3,61)=183 blocks = 0.7 blocks/CU (Occupancy 6.4%, 58.9us
// vs ~22us). B-direct weights + NCHUNK=13 were net positive (~-200us).
// R11: keep B-direct + NCHUNK=13; move out_proj back to the 64^2 kernel
// (grid 6x121=726 blocks) with ACT=4 combine restored there; in_proj blocks
// reordered m-major (SWAPXY, grid 61x12) so consecutive blocks share one
// 393KB weight panel (12 panels = 4.7MB > 4MB L2 thrashed in n-major order).
// Workspace: 57,981,952 floats = 232 MB.
// ---------------------------------------------------------------------------

constexpr int BZv = 16, SEQ = 5, NV = 1;
constexpr int C = 384, DSTATE = 16, DCONV = 4, NLAYER = 4;
constexpr int DI = 768;
constexpr int DTR = 24;
constexpr int NTOK = (NV + 2) * SEQ * 64;  // 960
constexpr int T = NTOK + 2;                // 962
constexpr int M = BZv * T;                 // 15392
constexpr int HB = 8;                      // batches per half
constexpr int MH = HB * T;                 // 7696 rows per half
constexpr int XZdim = 2 * DI;              // 1536
constexpr int ND = DTR + 2 * DSTATE;       // 56
constexpr int NDP = 32;                    // dt_r plane stride
constexpr int NCHUNK = 13, TC = 74;        // 13*74 == 962
constexpr int NQ = 241;                    // ceil(T/4) t-quads
constexpr size_t SEC_SZ = (size_t)BZv * SEQ * C * 64;

// swizzled weight set sizes (elements per (layer[,dir]) set)
constexpr size_t SET1 = (size_t)C * C;        // 147,456 (fc)
constexpr size_t SETI = (size_t)2 * DI * C;   // 589,824 (in_proj)
constexpr size_t SETO = (size_t)C * DI;       // 294,912 (out_proj)
constexpr size_t SETX = (size_t)64 * DI;      // 49,152  (x_proj, N padded 56->64)
constexpr size_t SETD = (size_t)DI * 32;      // 24,576  (dt_proj, K padded 24->32)
constexpr size_t WSZ1 = 4 * SET1;             // 589,824
constexpr size_t WSZI = 8 * SETI;             // 4,718,592
constexpr size_t WSZO = 8 * SETO;             // 2,359,296
constexpr size_t WSZX = 8 * SETX;             // 393,216
constexpr size_t WSZD = 8 * SETD;             // 196,608

typedef __attribute__((ext_vector_type(8))) short short8;
typedef __attribute__((ext_vector_type(4))) float floatx4;

#define GLOAD_LDS16(g, l)                                        \
  __builtin_amdgcn_global_load_lds(                              \
      (const __attribute__((address_space(1))) void*)(g),        \
      (__attribute__((address_space(3))) void*)(l), 16, 0, 0)

__device__ __forceinline__ void split_bf16(float v, short& hi, short& lo) {
  unsigned u = __float_as_uint(v);
  unsigned hib = u & 0xFFFF0000u;      // truncate to bf16
  float r = v - __uint_as_float(hib);  // exact residual
  hi = (short)(hib >> 16);
  lo = (short)(__float_as_uint(r) >> 16);
}

__device__ __forceinline__ float join_bf16(short h, short l) {
  return __uint_as_float((unsigned)(unsigned short)h << 16) +
         __uint_as_float((unsigned)(unsigned short)l << 16);
}

// e[s] = e1^(s+1), 15 muls, ~4 deep.
__device__ __forceinline__ void pow16(float e1, float* e) {
  e[0] = e1;
  e[1] = e1 * e1;
  e[3] = e[1] * e[1];
  e[7] = e[3] * e[3];
  e[15] = e[7] * e[7];
  e[2] = e[1] * e[0];
  e[4] = e[3] * e[0];
  e[5] = e[3] * e[1];
  e[6] = e[5] * e[0];
  e[8] = e[7] * e[0];
  e[9] = e[7] * e[1];
  e[10] = e[9] * e[0];
  e[11] = e[7] * e[3];
  e[12] = e[11] * e[0];
  e[13] = e[11] * e[1];
  e[14] = e[13] * e[0];
}

// ------------------------------ token assembly -----------------------------
// Blocks 0..719: (b, g_, cc) 64x128 tiles, LDS transpose, coalesced both
// ways, pe-add fused into the write pass. Block 720: gps tail rows.
__global__ __launch_bounds__(256) void assemble_t_k(
    const float* __restrict__ img, const float* __restrict__ lid,
    const float* __restrict__ rad, const float* __restrict__ gps,
    const float* __restrict__ pe, float* __restrict__ x) {
  __shared__ float lds[64][129];
  int blk = blockIdx.x, tid = threadIdx.x;
  if (blk < 720) {
    int b = blk / 45;
    int rem = blk % 45;
    int g_ = rem / 3, cc = rem % 3;
    int sec = g_ / 5, s = g_ % 5;
    int srow = b * 5 + s;
    int which = (cc + sec) % 3;
    const float* src = (which == 0) ? img : (which == 1 ? lid : rad);
    const float* sp = src + (size_t)srow * (C * 64) + cc * 8192;
#pragma unroll
    for (int i = 0; i < 32; i++) {
      int lin = tid + 256 * i;
      lds[lin & 63][lin >> 6] = sp[lin];
    }
    __syncthreads();
#pragma unroll
    for (int i = 0; i < 32; i++) {
      int lin = tid + 256 * i;
      int p = lin >> 7, c = lin & 127;
      int t = g_ * 64 + p;
      int ccc = cc * 128 + c;
      x[((size_t)b * T + t) * C + ccc] = lds[p][c] + pe[(size_t)t * C + ccc];
    }
  } else {
#pragma unroll
    for (int i = 0; i < 48; i++) {
      int lin = tid + 256 * i;
      int r = lin / C, c = lin % C;
      int b = r >> 1, e = r & 1;
      x[((size_t)b * T + NTOK + e) * C + c] =
          gps[((size_t)b * 2 + e) * C + c] + pe[(size_t)(NTOK + e) * C + c];
    }
  }
}

// -------------------- fused LN (stats + apply -> planes) -------------------
__global__ __launch_bounds__(256) void ln_fused_k(
    const float* __restrict__ x, const float* __restrict__ g,
    const float* __restrict__ b, short* __restrict__ oh,
    short* __restrict__ ol) {
  int row = blockIdx.x * 4 + (threadIdx.x >> 6);
  int lane = threadIdx.x & 63;
  const float* xr = x + (size_t)row * C;
  float v[6];
  float s = 0.f;
#pragma unroll
  for (int j = 0; j < 6; j++) {
    v[j] = xr[lane + 64 * j];
    s += v[j];
  }
#pragma unroll
  for (int o = 32; o > 0; o >>= 1) s += __shfl_xor(s, o, 64);
  float mean = s * (1.f / 384.f);
  float q = 0.f;
#pragma unroll
  for (int j = 0; j < 6; j++) {
    float d = v[j] - mean;
    q += d * d;
  }
#pragma unroll
  for (int o = 32; o > 0; o >>= 1) q += __shfl_xor(q, o, 64);
  float rstd = rsqrtf(q * (1.f / 384.f) + 1e-5f);
#pragma unroll
  for (int j = 0; j < 6; j++) {
    int c = lane + 64 * j;
    float val = (v[j] - mean) * rstd * g[c] + b[c];
    short h, l;
    split_bf16(val, h, l);
    oh[(size_t)row * C + c] = h;
    ol[(size_t)row * C + c] = l;
  }
}

// ------------------------- LN row stats (final LN) -------------------------
__global__ __launch_bounds__(256) void ln_stats2_k(const float* __restrict__ x,
                                                   float* __restrict__ stats) {
  int row = blockIdx.x * 4 + (threadIdx.x >> 6);
  int lane = threadIdx.x & 63;
  const float* xr = x + (size_t)row * C;
  float v[6];
  float s = 0.f;
#pragma unroll
  for (int j = 0; j < 6; j++) {
    v[j] = xr[lane + 64 * j];
    s += v[j];
  }
#pragma unroll
  for (int o = 32; o > 0; o >>= 1) s += __shfl_xor(s, o, 64);
  float mean = s * (1.f / 384.f);
  float q = 0.f;
#pragma unroll
  for (int j = 0; j < 6; j++) {
    float d = v[j] - mean;
    q += d * d;
  }
#pragma unroll
  for (int o = 32; o > 0; o >>= 1) q += __shfl_xor(q, o, 64);
  if (lane == 0) {
    stats[2 * row] = mean;
    stats[2 * row + 1] = rsqrtf(q * (1.f / 384.f) + 1e-5f);
  }
}

// ------------------ weight cast to swizzled fragment order -----------------
// Output layout per set: idx = ((nf*KS + ks)*64 + lane)*8 + e, holding
// W[n = nf*16 + (lane&15)][k = ks*32 + (lane>>4)*8 + e], zero-padded when
// n >= NSRC or k >= KSRC. grid: (NP*KS*32/256, nsets).
template <int NSRC, int KSRC, int KS>
__global__ __launch_bounds__(256) void cast_swz_k(const float* __restrict__ src,
                                                  short* __restrict__ oh,
                                                  short* __restrict__ ol) {
  constexpr int NP = (NSRC + 15) & ~15;
  constexpr size_t SETSZ = (size_t)NP * KS * 32;
  int set = blockIdx.y;
  size_t idx = (size_t)blockIdx.x * 256 + threadIdx.x;
  int e = (int)(idx & 7);
  int lane = (int)((idx >> 3) & 63);
  size_t rest = idx >> 9;
  int ks = (int)(rest % KS);
  int nf = (int)(rest / KS);
  int n = nf * 16 + (lane & 15);
  int k = ks * 32 + ((lane >> 4) << 3) + e;
  float v = 0.f;
  if (n < NSRC && k < KSRC)
    v = src[(size_t)set * NSRC * KSRC + (size_t)n * KSRC + k];
  short h, l;
  split_bf16(v, h, l);
  oh[(size_t)set * SETSZ + idx] = h;
  ol[(size_t)set * SETSZ + idx] = l;
}

// ------------------ split-bf16 MFMA GEMM (128x128, B-direct) ---------------
// ACT: 0 none, 1 lrelu(0.2).
// OSPLIT: write hi/lo planes (stride N). W in swizzled fragment order.
// SWAPXY: m-tiles on blockIdx.x (consecutive blocks share one B panel).
template <int ACT, bool BIAS, bool FLIPA, bool OSPLIT, bool SWAPXY>
__global__ __launch_bounds__(256) void mgemm_k(
    const short* __restrict__ Ah, const short* __restrict__ Al, int K,
    const short* __restrict__ Wh, const short* __restrict__ Wl, int N,
    const float* __restrict__ bias, float* __restrict__ Co, int ldc,
    short* __restrict__ Oh, short* __restrict__ Ol, int Mrows, int arow_off,
    int crow_off) {
  __shared__ __align__(16) short sAh[128 * 32];
  __shared__ __align__(16) short sAl[128 * 32];
  const int tid = threadIdx.x;
  const int wave = tid >> 6, lane = tid & 63;
  const int bm_ = SWAPXY ? blockIdx.x : blockIdx.y;
  const int bn_ = SWAPXY ? blockIdx.y : blockIdx.x;
  const int m0 = bm_ * 128, n0 = bn_ * 128;
  const int lrow = lane >> 2, lchunk = lane & 3;
  const int wm = (wave >> 1) * 64, wn = (wave & 1) * 64;
  const int frow = lane & 15, fquad = lane >> 4;
  const int KST = K >> 5;
  const int nfb = (n0 + wn) >> 4;

  size_t arow[2];
#pragma unroll
  for (int p = 0; p < 2; p++) {
    int r = p * 64 + wave * 16 + lrow;
    int lm = m0 + r;
    if (lm >= Mrows) lm = Mrows - 1;
    int g = arow_off + lm;
    if (FLIPA) {
      int bb = g / T;
      int tt = g - bb * T;
      g = bb * T + (T - 1 - tt);
    }
    arow[p] = (size_t)g * K;
  }

  floatx4 acc[4][4] = {};
  for (int k0 = 0; k0 < K; k0 += 32) {
    if (k0) __syncthreads();
    const int kc = k0 + lchunk * 8;
#pragma unroll
    for (int p = 0; p < 2; p++) {
      GLOAD_LDS16(Ah + arow[p] + kc, &sAh[(p * 64 + wave * 16) * 32]);
      GLOAD_LDS16(Al + arow[p] + kc, &sAl[(p * 64 + wave * 16) * 32]);
    }
    const int ks = k0 >> 5;
    short8 bh[4], bl[4];
#pragma unroll
    for (int j = 0; j < 4; j++) {
      size_t bo = (((size_t)(nfb + j) * KST + ks) * 64 + lane) * 8;
      bh[j] = *(const short8*)&Wh[bo];
      bl[j] = *(const short8*)&Wl[bo];
    }
    __syncthreads();
    short8 ah[4], al[4];
#pragma unroll
    for (int i = 0; i < 4; i++) {
      int ra = (wm + i * 16 + frow) * 32 + fquad * 8;
      ah[i] = *(const short8*)&sAh[ra];
      al[i] = *(const short8*)&sAl[ra];
    }
#pragma unroll
    for (int i = 0; i < 4; i++)
#pragma unroll
      for (int j = 0; j < 4; j++) {
        acc[i][j] = __builtin_amdgcn_mfma_f32_16x16x32_bf16(ah[i], bh[j],
                                                            acc[i][j], 0, 0, 0);
        acc[i][j] = __builtin_amdgcn_mfma_f32_16x16x32_bf16(al[i], bh[j],
                                                            acc[i][j], 0, 0, 0);
        acc[i][j] = __builtin_amdgcn_mfma_f32_16x16x32_bf16(ah[i], bl[j],
                                                            acc[i][j], 0, 0, 0);
      }
  }
#pragma unroll
  for (int i = 0; i < 4; i++) {
#pragma unroll
    for (int r = 0; r < 4; r++) {
      int gm = m0 + wm + i * 16 + fquad * 4 + r;
      if (gm >= Mrows) continue;
      int grow = crow_off + gm;
#pragma unroll
      for (int j = 0; j < 4; j++) {
        int gn = n0 + wn + j * 16 + frow;
        if (gn >= N) continue;
        float v = acc[i][j][r];
        if constexpr (BIAS) v += bias[gn];
        if constexpr (ACT == 1) v = v >= 0.f ? v : 0.2f * v;
        if constexpr (OSPLIT) {
          short h, l;
          split_bf16(v, h, l);
          Oh[(size_t)grow * N + gn] = h;
          Ol[(size_t)grow * N + gn] = l;
        } else {
          Co[(size_t)grow * ldc + gn] = v;
        }
      }
    }
  }
}

// ------------------- split-bf16 MFMA GEMM (64x64, B-direct) ----------------
// OMODE: 0 fp32 Co (stride ldc), 2 x_proj dual: planes (stride NDP) for
//        gn<32 AND fp32 Co[row*32 + gn-24] for gn>=24 (B/C region).
// ACT: 0 none, 2 fast-softplus, 4 combine v = e2*(e1 + v) (stride ldc).
template <int ACT, bool BIAS, int OMODE>
__global__ __launch_bounds__(256) void mgemm64_k(
    const short* __restrict__ Ah, const short* __restrict__ Al, int lda, int K,
    const short* __restrict__ Wh, const short* __restrict__ Wl, int N,
    const float* __restrict__ bias, float* __restrict__ Co, int ldc,
    short* __restrict__ Oh, short* __restrict__ Ol,
    const float* __restrict__ e1, const float* __restrict__ e2, int Mrows,
    int crow_off) {
  __shared__ __align__(16) short sAh[64 * 32];
  __shared__ __align__(16) short sAl[64 * 32];
  const int tid = threadIdx.x;
  const int wave = tid >> 6, lane = tid & 63;
  const int m0 = blockIdx.y * 64, n0 = blockIdx.x * 64;
  const int schunk = tid & 3;
  const int frow = lane & 15, fquad = lane >> 4;
  const int KST = K >> 5;
  const int nfw = (n0 >> 4) + wave;

  int lm = m0 + (tid >> 2);
  if (lm >= Mrows) lm = Mrows - 1;
  size_t aoff = (size_t)lm * lda;

  floatx4 acc[4] = {};
  for (int k0 = 0; k0 < K; k0 += 32) {
    if (k0) __syncthreads();
    const int kc = k0 + schunk * 8;
    GLOAD_LDS16(Ah + aoff + kc, &sAh[(wave * 16) * 32]);
    GLOAD_LDS16(Al + aoff + kc, &sAl[(wave * 16) * 32]);
    const int ks = k0 >> 5;
    short8 bh, bl;
    {
      size_t bo = (((size_t)nfw * KST + ks) * 64 + lane) * 8;
      bh = *(const short8*)&Wh[bo];
      bl = *(const short8*)&Wl[bo];
    }
    __syncthreads();
    short8 ah[4], al[4];
#pragma unroll
    for (int i = 0; i < 4; i++) {
      int ra = (i * 16 + frow) * 32 + fquad * 8;
      ah[i] = *(const short8*)&sAh[ra];
      al[i] = *(const short8*)&sAl[ra];
    }
#pragma unroll
    for (int i = 0; i < 4; i++) {
      acc[i] = __builtin_amdgcn_mfma_f32_16x16x32_bf16(ah[i], bh, acc[i], 0, 0, 0);
      acc[i] = __builtin_amdgcn_mfma_f32_16x16x32_bf16(al[i], bh, acc[i], 0, 0, 0);
      acc[i] = __builtin_amdgcn_mfma_f32_16x16x32_bf16(ah[i], bl, acc[i], 0, 0, 0);
    }
  }
  const int gn = n0 + wave * 16 + frow;
  if (gn < N) {
#pragma unroll
    for (int i = 0; i < 4; i++) {
#pragma unroll
      for (int r = 0; r < 4; r++) {
        int gm = m0 + i * 16 + fquad * 4 + r;
        if (gm >= Mrows) continue;
        int grow = crow_off + gm;
        float v = acc[i][r];
        if constexpr (BIAS) v += bias[gn];
        if constexpr (ACT == 2) v = (v > 20.f) ? v : __logf(1.f + __expf(v));
        if constexpr (ACT == 4) {
          size_t o = (size_t)grow * ldc + gn;
          v = e2[o] * (e1[o] + v);
        }
        if constexpr (OMODE == 2) {
          if (gn < NDP) {
            short h, l;
            split_bf16(v, h, l);
            Oh[(size_t)grow * NDP + gn] = h;
            Ol[(size_t)grow * NDP + gn] = l;
          }
          if (gn >= DTR) Co[(size_t)grow * 32 + (gn - DTR)] = v;
        } else {
          Co[(size_t)grow * ldc + gn] = v;
        }
      }
    }
  }
}

// --------------------------- depthwise conv + silu -------------------------
__global__ __launch_bounds__(256) void conv_k(const float* __restrict__ xz,
                                              const float* __restrict__ cw,
                                              const float* __restrict__ cb,
                                              short* __restrict__ xch,
                                              short* __restrict__ xcl) {
  int idx = blockIdx.x * 256 + threadIdx.x;  // [0, HB*NQ*384)
  int dh = idx % (DI / 2);
  int rem = idx / (DI / 2);
  int q = rem % NQ;
  int b = rem / NQ;
  int d = dh * 2;
  int t0 = q * 4;
  const float* base = xz + (size_t)b * T * XZdim + d;
  float4 cwa = *(const float4*)&cw[d * 4];
  float4 cwb = *(const float4*)&cw[(d + 1) * 4];
  float cb0 = cb[d], cb1 = cb[d + 1];
  float2 w[7];
#pragma unroll
  for (int j = 0; j < 7; j++) {
    int tt = t0 - 3 + j;
    w[j] = (tt >= 0 && tt < T) ? *(const float2*)(base + (size_t)tt * XZdim)
                               : make_float2(0.f, 0.f);
  }
  const float cwx[4] = {cwa.x, cwa.y, cwa.z, cwa.w};
  const float cwy[4] = {cwb.x, cwb.y, cwb.z, cwb.w};
#pragma unroll
  for (int r = 0; r < 4; r++) {
    int t = t0 + r;
    if (t >= T) break;
    float a0 = cb0, a1 = cb1;
#pragma unroll
    for (int j = 0; j < 4; j++) {
      a0 += w[r + j].x * cwx[j];
      a1 += w[r + j].y * cwy[j];
    }
    float v0 = a0 / (1.f + __expf(-a0));
    float v1 = a1 / (1.f + __expf(-a1));
    short h0, l0, h1, l1;
    split_bf16(v0, h0, l0);
    split_bf16(v1, h1, l1);
    size_t o = ((size_t)b * T + t) * DI + d;
    *(short2*)&xch[o] = make_short2(h0, h1);
    *(short2*)&xcl[o] = make_short2(l0, l1);
  }
}

// ----------------------- chunked selective scan ----------------------------
// Phase 1: local scan from h=0; stores h_local[16] + sum(dt) per (b,ch,d).
__global__ __launch_bounds__(256) void scan_p1_k(
    const float* __restrict__ xzb, const short* __restrict__ xch,
    const short* __restrict__ xcl, const float* __restrict__ xdbc,
    const float* __restrict__ alog, float* __restrict__ hchk,
    float* __restrict__ sdt) {
  int d = blockIdx.x * 256 + threadIdx.x;
  int ch = blockIdx.y, b = blockIdx.z;
  float A[DSTATE], h[DSTATE];
  bool powA = true;
#pragma unroll
  for (int s = 0; s < DSTATE; s++) {
    A[s] = -expf(alog[d * DSTATE + s]);
    powA = powA && (fabsf(A[s] + (float)(s + 1)) <= 1e-4f * (float)(s + 1));
    h[s] = 0.f;
  }
  const int t0 = ch * TC;
  const float* xzr = xzb + ((size_t)b * T + t0) * XZdim;
  const short* xchr = xch + ((size_t)b * T + t0) * DI;
  const short* xclr = xcl + ((size_t)b * T + t0) * DI;
  const float* bcr = xdbc + ((size_t)b * T + t0) * 32;
  float sd = 0.f;
  if (powA) {
    for (int t = 0; t < TC; t++) {
      float dt = xzr[(size_t)t * XZdim + d];
      float xv = join_bf16(xchr[(size_t)t * DI + d], xclr[(size_t)t * DI + d]);
      float dx = dt * xv;
      const float* bc = bcr + (size_t)t * 32;
      sd += dt;
      float ev[DSTATE];
      pow16(__expf(-dt), ev);
#pragma unroll
      for (int s = 0; s < DSTATE; s++) h[s] = h[s] * ev[s] + dx * bc[s];
    }
  } else {
    for (int t = 0; t < TC; t++) {
      float dt = xzr[(size_t)t * XZdim + d];
      float xv = join_bf16(xchr[(size_t)t * DI + d], xclr[(size_t)t * DI + d]);
      float dx = dt * xv;
      const float* bc = bcr + (size_t)t * 32;
      sd += dt;
#pragma unroll
      for (int s = 0; s < DSTATE; s++)
        h[s] = h[s] * __expf(dt * A[s]) + dx * bc[s];
    }
  }
  size_t o = ((size_t)(b * NCHUNK + ch) * DSTATE) * DI + d;
#pragma unroll
  for (int s = 0; s < DSTATE; s++) hchk[o + (size_t)s * DI] = h[s];
  sdt[(size_t)(b * NCHUNK + ch) * DI + d] = sd;
}

// Phase 2: per (b,s,d), NCHUNK-chunk recurrence; P recomputed from sdt.
__global__ __launch_bounds__(256) void scan_p2_k(float* __restrict__ hchk,
                                                 const float* __restrict__ sdt,
                                                 const float* __restrict__ alog) {
  int idx = blockIdx.x * 256 + threadIdx.x;  // [0, HB*DSTATE*DI)
  int d = idx % DI;
  int rem = idx / DI;
  int s = rem % DSTATE, b = rem / DSTATE;
  float A = -expf(alog[d * DSTATE + s]);
  float hin = 0.f;
#pragma unroll
  for (int ch = 0; ch < NCHUNK; ch++) {
    size_t o = ((size_t)(b * NCHUNK + ch) * DSTATE + s) * DI + d;
    float P = __expf(A * sdt[(size_t)(b * NCHUNK + ch) * DI + d]);
    float hl = hchk[o];
    hchk[o] = hin;
    hin = P * hin + hl;
  }
}

// Phase 3: rescan from incoming state; y = h.C + D*x, gated silu(z) -> planes.
__global__ __launch_bounds__(256) void scan_p3_k(
    const float* __restrict__ xzb, const short* __restrict__ xch,
    const short* __restrict__ xcl, const float* __restrict__ xdbc,
    const float* __restrict__ alog, const float* __restrict__ Dp,
    const float* __restrict__ hchk, short* __restrict__ yh,
    short* __restrict__ yl) {
  int d = blockIdx.x * 256 + threadIdx.x;
  int ch = blockIdx.y, b = blockIdx.z;
  float A[DSTATE], h[DSTATE];
  bool powA = true;
  size_t o = ((size_t)(b * NCHUNK + ch) * DSTATE) * DI + d;
#pragma unroll
  for (int s = 0; s < DSTATE; s++) {
    A[s] = -expf(alog[d * DSTATE + s]);
    powA = powA && (fabsf(A[s] + (float)(s + 1)) <= 1e-4f * (float)(s + 1));
    h[s] = hchk[o + (size_t)s * DI];
  }
  float Dd = Dp[d];
  const int t0 = ch * TC;
  const float* xzr = xzb + ((size_t)b * T + t0) * XZdim;
  const short* xchr = xch + ((size_t)b * T + t0) * DI;
  const short* xclr = xcl + ((size_t)b * T + t0) * DI;
  const float* bcr = xdbc + ((size_t)b * T + t0) * 32;
  if (powA) {
    for (int t = 0; t < TC; t++) {
      float dt = xzr[(size_t)t * XZdim + d];
      float xv = join_bf16(xchr[(size_t)t * DI + d], xclr[(size_t)t * DI + d]);
      float zv = xzr[(size_t)t * XZdim + DI + d];
      float dx = dt * xv;
      float accv = 0.f;
      const float* bc = bcr + (size_t)t * 32;
      float ev[DSTATE];
      pow16(__expf(-dt), ev);
#pragma unroll
      for (int s = 0; s < DSTATE; s++) {
        h[s] = h[s] * ev[s] + dx * bc[s];
        accv += h[s] * bc[DSTATE + s];
      }
      float y = accv + Dd * xv;
      float sz = zv / (1.f + __expf(-zv));
      float v = y * sz;
      short hh, ll;
      split_bf16(v, hh, ll);
      size_t oi = ((size_t)(b * T + t0 + t)) * DI + d;
      yh[oi] = hh;
      yl[oi] = ll;
    }
  } else {
    for (int t = 0; t < TC; t++) {
      float dt = xzr[(size_t)t * XZdim + d];
      float xv = join_bf16(xchr[(size_t)t * DI + d], xclr[(size_t)t * DI + d]);
      float zv = xzr[(size_t)t * XZdim + DI + d];
      float dx = dt * xv;
      float accv = 0.f;
      const float* bc = bcr + (size_t)t * 32;
#pragma unroll
      for (int s = 0; s < DSTATE; s++) {
        h[s] = h[s] * __expf(dt * A[s]) + dx * bc[s];
        accv += h[s] * bc[DSTATE + s];
      }
      float y = accv + Dd * xv;
      float sz = zv / (1.f + __expf(-zv));
      float v = y * sz;
      short hh, ll;
      split_bf16(v, hh, ll);
      size_t oi = ((size_t)(b * T + t0 + t)) * DI + d;
      yh[oi] = hh;
      yl[oi] = ll;
    }
  }
}

// ---------------- final LN + transpose scatter (contiguous writes) ---------
__global__ __launch_bounds__(256) void ln_scatter_k(
    const float* __restrict__ x, const float* __restrict__ stats,
    const float* __restrict__ g, const float* __restrict__ bb,
    float* __restrict__ out) {
  __shared__ float lds[64][129];
  int blk = blockIdx.x, tid = threadIdx.x;
  if (blk < 240) {
    int b = blk / 15, g_ = blk % 15;
    int sec = g_ / 5, s = g_ % 5;
    const int rbase = b * T + g_ * 64;
    for (int cc = 0; cc < 3; cc++) {
      if (cc) __syncthreads();
#pragma unroll
      for (int i = 0; i < 32; i++) {
        int lin = tid + 256 * i;  // [0, 8192)
        int p = lin >> 7, c = lin & 127;
        int row = rbase + p;
        int ccc = cc * 128 + c;
        float v = x[(size_t)row * C + ccc];
        v = (v - stats[2 * row]) * stats[2 * row + 1] * g[ccc] + bb[ccc];
        lds[p][c] = v;
      }
      __syncthreads();
      size_t obase = (size_t)sec * SEC_SZ +
                     (((size_t)(b * 5 + s) * C + cc * 128) << 6);
#pragma unroll
      for (int i = 0; i < 32; i++) {
        int lin = tid + 256 * i;
        int c = lin >> 6, p = lin & 63;
        out[obase + ((size_t)c << 6) + p] = lds[p][c];
      }
    }
  } else {
#pragma unroll
    for (int i = 0; i < 48; i++) {
      int lin = tid + 256 * i;
      int r = lin / C, c = lin % C;
      int b = r >> 1, e = r & 1;
      int row = b * T + NTOK + e;
      float v = x[(size_t)row * C + c];
      v = (v - stats[2 * row]) * stats[2 * row + 1] * g[c] + bb[c];
      out[3 * SEC_SZ + ((size_t)(b * 2 + e)) * C + c] = v;
    }
  }
}

// --------------------------------- launch ----------------------------------
extern "C" void kernel_launch(void* const* d_in, const int* in_sizes, int n_in,
                              void* d_out, int out_size, void* d_ws,
                              size_t ws_size, hipStream_t stream) {
  const float* image = (const float*)d_in[0];
  const float* lidar = (const float*)d_in[1];
  const float* radar = (const float*)d_in[2];
  const float* gps = (const float*)d_in[3];
  const float* pe = (const float*)d_in[4];
  const float* ln1g = (const float*)d_in[5];
  const float* ln1b = (const float*)d_in[6];
  const float* fc1w = (const float*)d_in[7];
  const float* fc1b = (const float*)d_in[8];
  const float* fc2w = (const float*)d_in[9];
  const float* fc2b_ = (const float*)d_in[10];
  const float* inw = (const float*)d_in[11];
  const float* cw = (const float*)d_in[12];
  const float* cb = (const float*)d_in[13];
  const float* xw = (const float*)d_in[14];
  const float* dtw = (const float*)d_in[15];
  const float* dtb = (const float*)d_in[16];
  const float* alog = (const float*)d_in[17];
  const float* Dp = (const float*)d_in[18];
  const float* ow = (const float*)d_in[19];
  const float* lnfg = (const float*)d_in[20];
  const float* lnfb = (const float*)d_in[21];
  float* out = (float*)d_out;

  // ---------------- workspace carve-up (57,981,952 floats = 232 MB) --------
  constexpr size_t MC = (size_t)M * C;  // 5,910,528
  float* ws = (float*)d_ws;
  float* x = ws;                            // MC
  float* fcb = x + MC;                      // MC (fc2 lrelu result)
  float* bmfm = fcb + MC;                   // MC (ln planes alias; then bm)
  float* x1f = bmfm + MC;                   // MC (x1 planes)
  float* yf = x1f + MC;                     // MC (y planes, half-local)
  float* xz_h = yf + MC;                    // MH*1536
  float* xcp = xz_h + (size_t)MH * XZdim;   // MH*DI floats (xc planes)
  float* xdp = xcp + (size_t)MH * DI;       // MH*64 floats (dt planes + B/C)
  constexpr size_t CHK_H = (size_t)HB * NCHUNK * DSTATE * DI;  // 1,277,952
  float* hchk = xdp + (size_t)MH * 64;
  float* sdtb = hchk + CHK_H;               // HB*NCHUNK*DI = 79,872
  float* wpl = sdtb + (size_t)HB * NCHUNK * DI;
  float* stats2 = hchk;  // final-LN stats alias (hchk dead by then)

  short* lnh = (short*)bmfm;  // ln planes dead before bm written
  short* lnl = lnh + MC;
  float* bm = bmfm;  // dir1 out_proj result (fp32, full M)
  short* x1h = (short*)x1f;
  short* x1l = x1h + MC;
  short* yh = (short*)yf;
  short* yl = yh + (size_t)MH * DI;
  short* xch = (short*)xcp;
  short* xcl = xch + (size_t)MH * DI;
  short* xdh = (short*)xdp;                  // MH*32 shorts (dt_r hi plane)
  short* xdl = xdh + (size_t)MH * NDP;       // MH*32 shorts (dt_r lo plane)
  float* xdbc = xdp + (size_t)MH * 32;       // MH*32 floats (fp32 B|C)

  short* wf1h = (short*)wpl;
  short* wf1l = wf1h + WSZ1;
  short* wf2h = wf1l + WSZ1;
  short* wf2l = wf2h + WSZ1;
  short* winh = wf2l + WSZ1;
  short* winl = winh + WSZI;
  short* wowh = winl + WSZI;
  short* wowl = wowh + WSZO;
  short* wxh = wowl + WSZO;
  short* wxl = wxh + WSZX;
  short* wdth = wxl + WSZX;
  short* wdtl = wdth + WSZD;

  // ------------- weight casts to swizzled fragment order (per call) --------
  cast_swz_k<C, C, 12><<<dim3((int)(SET1 / 256), 4), 256, 0, stream>>>(
      fc1w, wf1h, wf1l);
  cast_swz_k<C, C, 12><<<dim3((int)(SET1 / 256), 4), 256, 0, stream>>>(
      fc2w, wf2h, wf2l);
  cast_swz_k<2 * DI, C, 12><<<dim3((int)(SETI / 256), 8), 256, 0, stream>>>(
      inw, winh, winl);
  cast_swz_k<C, DI, 24><<<dim3((int)(SETO / 256), 8), 256, 0, stream>>>(
      ow, wowh, wowl);
  cast_swz_k<ND, DI, 24><<<dim3((int)(SETX / 256), 8), 256, 0, stream>>>(
      xw, wxh, wxl);
  cast_swz_k<DI, DTR, 1><<<dim3((int)(SETD / 256), 8), 256, 0, stream>>>(
      dtw, wdth, wdtl);

  assemble_t_k<<<721, 256, 0, stream>>>(image, lidar, radar, gps, pe, x);

  for (int l = 0; l < NLAYER; l++) {
    ln_fused_k<<<M / 4, 256, 0, stream>>>(x, ln1g + l * C, ln1b + l * C, lnh,
                                          lnl);
    // fc1 = LN(x) @ fc1_w^T + b -> bf16 planes (full M)
    mgemm_k<0, true, false, true, false><<<dim3(3, 121), 256, 0, stream>>>(
        lnh, lnl, C, wf1h + l * SET1, wf1l + l * SET1, C, fc1b + l * C,
        nullptr, 0, x1h, x1l, M, 0, 0);
    // fcb = lrelu(flip(xfc1) @ fc2_w^T + b) -> fp32 (full M)
    mgemm_k<1, true, true, false, false><<<dim3(3, 121), 256, 0, stream>>>(
        x1h, x1l, C, wf2h + l * SET1, wf2l + l * SET1, C, fc2b_ + l * C, fcb,
        C, nullptr, nullptr, M, 0, 0);
    // dir1 (backward) first -> bm; dir0 last fuses combine into x.
    for (int di = 0; di < 2; di++) {
      const int dir = 1 - di;
      size_t wo = (size_t)(l * 2 + dir);
      for (int h = 0; h < 2; h++) {
        const int roff = h * MH;
        // in_proj -> xz_h (dir1 reads time-flipped rows of x1); m-major grid
        if (dir == 0)
          mgemm_k<0, false, false, false, true><<<dim3(61, 12), 256, 0, stream>>>(
              x1h, x1l, C, winh + wo * SETI, winl + wo * SETI, 2 * DI, nullptr,
              xz_h, XZdim, nullptr, nullptr, MH, roff, 0);
        else
          mgemm_k<0, false, true, false, true><<<dim3(61, 12), 256, 0, stream>>>(
              x1h, x1l, C, winh + wo * SETI, winl + wo * SETI, 2 * DI, nullptr,
              xz_h, XZdim, nullptr, nullptr, MH, roff, 0);
        // causal depthwise conv + silu -> xc planes (4-t quad)
        conv_k<<<(HB * NQ * (DI / 2)) / 256, 256, 0, stream>>>(
            xz_h, cw + wo * DI * DCONV, cb + wo * DI, xch, xcl);
        // x_proj -> dt_r planes (stride 32) + fp32 B/C (xdbc)
        mgemm64_k<0, false, 2><<<dim3(1, 121), 256, 0, stream>>>(
            xch, xcl, DI, DI, wxh + wo * SETX, wxl + wo * SETX, ND, nullptr,
            xdbc, 0, xdh, xdl, nullptr, nullptr, MH, 0);
        // dt_proj (K padded 24->32, zero weight pad) + fast softplus -> xz dt
        mgemm64_k<2, true, 0><<<dim3(12, 121), 256, 0, stream>>>(
            xdh, xdl, NDP, 32, wdth + wo * SETD, wdtl + wo * SETD, DI,
            dtb + wo * DI, xz_h, XZdim, nullptr, nullptr, nullptr, nullptr,
            MH, 0);
        // chunked selective scan -> y planes
        scan_p1_k<<<dim3(3, NCHUNK, HB), 256, 0, stream>>>(
            xz_h, xch, xcl, xdbc, alog + wo * DI * DSTATE, hchk, sdtb);
        scan_p2_k<<<(HB * DSTATE * DI) / 256, 256, 0, stream>>>(
            hchk, sdtb, alog + wo * DI * DSTATE);
        scan_p3_k<<<dim3(3, NCHUNK, HB), 256, 0, stream>>>(
            xz_h, xch, xcl, xdbc, alog + wo * DI * DSTATE, Dp + wo * DI, hchk,
            yh, yl);
        // out_proj (64^2, 726 blocks): dir1 -> bm; dir0 -> x = bm*(fcb + v)
        if (dir == 1)
          mgemm64_k<0, false, 0><<<dim3(6, 121), 256, 0, stream>>>(
              yh, yl, DI, DI, wowh + wo * SETO, wowl + wo * SETO, C, nullptr,
              bm, C, nullptr, nullptr, nullptr, nullptr, MH, roff);
        else
          mgemm64_k<4, false, 0><<<dim3(6, 121), 256, 0, stream>>>(
              yh, yl, DI, DI, wowh + wo * SETO, wowl + wo * SETO, C, nullptr,
              x, C, nullptr, nullptr, fcb, bm, MH, roff);
      }
    }
  }
  ln_stats2_k<<<M / 4, 256, 0, stream>>>(x, stats2);
  ln_scatter_k<<<241, 256, 0, stream>>>(x, stats2, lnfg, lnfb, out);
}

// Round 4
// 3067.558 us; speedup vs baseline: 1.1325x; 1.0904x over previous
//
#include <hip/hip_runtime.h>
#include <cstdint>
#include <cstddef>

// ---------------------------------------------------------------------------
// MambaFusion. R12 (on R11):
// R11 post-mortem: scan_p3 top kernel (47.6us, Occ 10.9%, VALU 28%, HBM 17%
// = latency-bound). NCHUNK 26->13 serialized the scan (312 blocks, 74-step
// chains); the +254us vs R9 is fully the scan regression.
// R12: NCHUNK=26 restored (624 blocks, TC=37). hchk+sdtb alias into the
// UPPER HALF of x (dead from ln_fused until the dir0 combines, which write
// after each call's p3) -> workspace 226.6MB, under R9's known-good 237.2.
// x_proj: new MT=16 tile variant of mgemm64 (grid 1x481 vs 1x121; the same
// 0.5-blocks/CU starvation as R10's out_proj mistake, measured there).
// ---------------------------------------------------------------------------

constexpr int BZv = 16, SEQ = 5, NV = 1;
constexpr int C = 384, DSTATE = 16, DCONV = 4, NLAYER = 4;
constexpr int DI = 768;
constexpr int DTR = 24;
constexpr int NTOK = (NV + 2) * SEQ * 64;  // 960
constexpr int T = NTOK + 2;                // 962
constexpr int M = BZv * T;                 // 15392
constexpr int HB = 8;                      // batches per half
constexpr int MH = HB * T;                 // 7696 rows per half
constexpr int XZdim = 2 * DI;              // 1536
constexpr int ND = DTR + 2 * DSTATE;       // 56
constexpr int NDP = 32;                    // dt_r plane stride
constexpr int NCHUNK = 26, TC = 37;        // 26*37 == 962
constexpr int NQ = 241;                    // ceil(T/4) t-quads
constexpr size_t SEC_SZ = (size_t)BZv * SEQ * C * 64;

// swizzled weight set sizes (elements per (layer[,dir]) set)
constexpr size_t SET1 = (size_t)C * C;        // 147,456 (fc)
constexpr size_t SETI = (size_t)2 * DI * C;   // 589,824 (in_proj)
constexpr size_t SETO = (size_t)C * DI;       // 294,912 (out_proj)
constexpr size_t SETX = (size_t)64 * DI;      // 49,152  (x_proj, N pad 56->64)
constexpr size_t SETD = (size_t)DI * 32;      // 24,576  (dt_proj, K pad 24->32)
constexpr size_t WSZ1 = 4 * SET1;             // 589,824
constexpr size_t WSZI = 8 * SETI;             // 4,718,592
constexpr size_t WSZO = 8 * SETO;             // 2,359,296
constexpr size_t WSZX = 8 * SETX;             // 393,216
constexpr size_t WSZD = 8 * SETD;             // 196,608

typedef __attribute__((ext_vector_type(8))) short short8;
typedef __attribute__((ext_vector_type(4))) float floatx4;

#define GLOAD_LDS16(g, l)                                        \
  __builtin_amdgcn_global_load_lds(                              \
      (const __attribute__((address_space(1))) void*)(g),        \
      (__attribute__((address_space(3))) void*)(l), 16, 0, 0)

__device__ __forceinline__ void split_bf16(float v, short& hi, short& lo) {
  unsigned u = __float_as_uint(v);
  unsigned hib = u & 0xFFFF0000u;      // truncate to bf16
  float r = v - __uint_as_float(hib);  // exact residual
  hi = (short)(hib >> 16);
  lo = (short)(__float_as_uint(r) >> 16);
}

__device__ __forceinline__ float join_bf16(short h, short l) {
  return __uint_as_float((unsigned)(unsigned short)h << 16) +
         __uint_as_float((unsigned)(unsigned short)l << 16);
}

// e[s] = e1^(s+1), 15 muls, ~4 deep.
__device__ __forceinline__ void pow16(float e1, float* e) {
  e[0] = e1;
  e[1] = e1 * e1;
  e[3] = e[1] * e[1];
  e[7] = e[3] * e[3];
  e[15] = e[7] * e[7];
  e[2] = e[1] * e[0];
  e[4] = e[3] * e[0];
  e[5] = e[3] * e[1];
  e[6] = e[5] * e[0];
  e[8] = e[7] * e[0];
  e[9] = e[7] * e[1];
  e[10] = e[9] * e[0];
  e[11] = e[7] * e[3];
  e[12] = e[11] * e[0];
  e[13] = e[11] * e[1];
  e[14] = e[13] * e[0];
}

// ------------------------------ token assembly -----------------------------
__global__ __launch_bounds__(256) void assemble_t_k(
    const float* __restrict__ img, const float* __restrict__ lid,
    const float* __restrict__ rad, const float* __restrict__ gps,
    const float* __restrict__ pe, float* __restrict__ x) {
  __shared__ float lds[64][129];
  int blk = blockIdx.x, tid = threadIdx.x;
  if (blk < 720) {
    int b = blk / 45;
    int rem = blk % 45;
    int g_ = rem / 3, cc = rem % 3;
    int sec = g_ / 5, s = g_ % 5;
    int srow = b * 5 + s;
    int which = (cc + sec) % 3;
    const float* src = (which == 0) ? img : (which == 1 ? lid : rad);
    const float* sp = src + (size_t)srow * (C * 64) + cc * 8192;
#pragma unroll
    for (int i = 0; i < 32; i++) {
      int lin = tid + 256 * i;
      lds[lin & 63][lin >> 6] = sp[lin];
    }
    __syncthreads();
#pragma unroll
    for (int i = 0; i < 32; i++) {
      int lin = tid + 256 * i;
      int p = lin >> 7, c = lin & 127;
      int t = g_ * 64 + p;
      int ccc = cc * 128 + c;
      x[((size_t)b * T + t) * C + ccc] = lds[p][c] + pe[(size_t)t * C + ccc];
    }
  } else {
#pragma unroll
    for (int i = 0; i < 48; i++) {
      int lin = tid + 256 * i;
      int r = lin / C, c = lin % C;
      int b = r >> 1, e = r & 1;
      x[((size_t)b * T + NTOK + e) * C + c] =
          gps[((size_t)b * 2 + e) * C + c] + pe[(size_t)(NTOK + e) * C + c];
    }
  }
}

// -------------------- fused LN (stats + apply -> planes) -------------------
__global__ __launch_bounds__(256) void ln_fused_k(
    const float* __restrict__ x, const float* __restrict__ g,
    const float* __restrict__ b, short* __restrict__ oh,
    short* __restrict__ ol) {
  int row = blockIdx.x * 4 + (threadIdx.x >> 6);
  int lane = threadIdx.x & 63;
  const float* xr = x + (size_t)row * C;
  float v[6];
  float s = 0.f;
#pragma unroll
  for (int j = 0; j < 6; j++) {
    v[j] = xr[lane + 64 * j];
    s += v[j];
  }
#pragma unroll
  for (int o = 32; o > 0; o >>= 1) s += __shfl_xor(s, o, 64);
  float mean = s * (1.f / 384.f);
  float q = 0.f;
#pragma unroll
  for (int j = 0; j < 6; j++) {
    float d = v[j] - mean;
    q += d * d;
  }
#pragma unroll
  for (int o = 32; o > 0; o >>= 1) q += __shfl_xor(q, o, 64);
  float rstd = rsqrtf(q * (1.f / 384.f) + 1e-5f);
#pragma unroll
  for (int j = 0; j < 6; j++) {
    int c = lane + 64 * j;
    float val = (v[j] - mean) * rstd * g[c] + b[c];
    short h, l;
    split_bf16(val, h, l);
    oh[(size_t)row * C + c] = h;
    ol[(size_t)row * C + c] = l;
  }
}

// ------------------------- LN row stats (final LN) -------------------------
__global__ __launch_bounds__(256) void ln_stats2_k(const float* __restrict__ x,
                                                   float* __restrict__ stats) {
  int row = blockIdx.x * 4 + (threadIdx.x >> 6);
  int lane = threadIdx.x & 63;
  const float* xr = x + (size_t)row * C;
  float v[6];
  float s = 0.f;
#pragma unroll
  for (int j = 0; j < 6; j++) {
    v[j] = xr[lane + 64 * j];
    s += v[j];
  }
#pragma unroll
  for (int o = 32; o > 0; o >>= 1) s += __shfl_xor(s, o, 64);
  float mean = s * (1.f / 384.f);
  float q = 0.f;
#pragma unroll
  for (int j = 0; j < 6; j++) {
    float d = v[j] - mean;
    q += d * d;
  }
#pragma unroll
  for (int o = 32; o > 0; o >>= 1) q += __shfl_xor(q, o, 64);
  if (lane == 0) {
    stats[2 * row] = mean;
    stats[2 * row + 1] = rsqrtf(q * (1.f / 384.f) + 1e-5f);
  }
}

// ------------------ weight cast to swizzled fragment order -----------------
// Output layout per set: idx = ((nf*KS + ks)*64 + lane)*8 + e, holding
// W[n = nf*16 + (lane&15)][k = ks*32 + (lane>>4)*8 + e], zero-padded when
// n >= NSRC or k >= KSRC. grid: (NP*KS*32/256, nsets).
template <int NSRC, int KSRC, int KS>
__global__ __launch_bounds__(256) void cast_swz_k(const float* __restrict__ src,
                                                  short* __restrict__ oh,
                                                  short* __restrict__ ol) {
  constexpr int NP = (NSRC + 15) & ~15;
  constexpr size_t SETSZ = (size_t)NP * KS * 32;
  int set = blockIdx.y;
  size_t idx = (size_t)blockIdx.x * 256 + threadIdx.x;
  int e = (int)(idx & 7);
  int lane = (int)((idx >> 3) & 63);
  size_t rest = idx >> 9;
  int ks = (int)(rest % KS);
  int nf = (int)(rest / KS);
  int n = nf * 16 + (lane & 15);
  int k = ks * 32 + ((lane >> 4) << 3) + e;
  float v = 0.f;
  if (n < NSRC && k < KSRC)
    v = src[(size_t)set * NSRC * KSRC + (size_t)n * KSRC + k];
  short h, l;
  split_bf16(v, h, l);
  oh[(size_t)set * SETSZ + idx] = h;
  ol[(size_t)set * SETSZ + idx] = l;
}

// ------------------ split-bf16 MFMA GEMM (128x128, B-direct) ---------------
// ACT: 0 none, 1 lrelu(0.2).
// OSPLIT: write hi/lo planes (stride N). W in swizzled fragment order.
// SWAPXY: m-tiles on blockIdx.x (consecutive blocks share one B panel).
template <int ACT, bool BIAS, bool FLIPA, bool OSPLIT, bool SWAPXY>
__global__ __launch_bounds__(256) void mgemm_k(
    const short* __restrict__ Ah, const short* __restrict__ Al, int K,
    const short* __restrict__ Wh, const short* __restrict__ Wl, int N,
    const float* __restrict__ bias, float* __restrict__ Co, int ldc,
    short* __restrict__ Oh, short* __restrict__ Ol, int Mrows, int arow_off,
    int crow_off) {
  __shared__ __align__(16) short sAh[128 * 32];
  __shared__ __align__(16) short sAl[128 * 32];
  const int tid = threadIdx.x;
  const int wave = tid >> 6, lane = tid & 63;
  const int bm_ = SWAPXY ? blockIdx.x : blockIdx.y;
  const int bn_ = SWAPXY ? blockIdx.y : blockIdx.x;
  const int m0 = bm_ * 128, n0 = bn_ * 128;
  const int lrow = lane >> 2, lchunk = lane & 3;
  const int wm = (wave >> 1) * 64, wn = (wave & 1) * 64;
  const int frow = lane & 15, fquad = lane >> 4;
  const int KST = K >> 5;
  const int nfb = (n0 + wn) >> 4;

  size_t arow[2];
#pragma unroll
  for (int p = 0; p < 2; p++) {
    int r = p * 64 + wave * 16 + lrow;
    int lm = m0 + r;
    if (lm >= Mrows) lm = Mrows - 1;
    int g = arow_off + lm;
    if (FLIPA) {
      int bb = g / T;
      int tt = g - bb * T;
      g = bb * T + (T - 1 - tt);
    }
    arow[p] = (size_t)g * K;
  }

  floatx4 acc[4][4] = {};
  for (int k0 = 0; k0 < K; k0 += 32) {
    if (k0) __syncthreads();
    const int kc = k0 + lchunk * 8;
#pragma unroll
    for (int p = 0; p < 2; p++) {
      GLOAD_LDS16(Ah + arow[p] + kc, &sAh[(p * 64 + wave * 16) * 32]);
      GLOAD_LDS16(Al + arow[p] + kc, &sAl[(p * 64 + wave * 16) * 32]);
    }
    const int ks = k0 >> 5;
    short8 bh[4], bl[4];
#pragma unroll
    for (int j = 0; j < 4; j++) {
      size_t bo = (((size_t)(nfb + j) * KST + ks) * 64 + lane) * 8;
      bh[j] = *(const short8*)&Wh[bo];
      bl[j] = *(const short8*)&Wl[bo];
    }
    __syncthreads();
    short8 ah[4], al[4];
#pragma unroll
    for (int i = 0; i < 4; i++) {
      int ra = (wm + i * 16 + frow) * 32 + fquad * 8;
      ah[i] = *(const short8*)&sAh[ra];
      al[i] = *(const short8*)&sAl[ra];
    }
#pragma unroll
    for (int i = 0; i < 4; i++)
#pragma unroll
      for (int j = 0; j < 4; j++) {
        acc[i][j] = __builtin_amdgcn_mfma_f32_16x16x32_bf16(ah[i], bh[j],
                                                            acc[i][j], 0, 0, 0);
        acc[i][j] = __builtin_amdgcn_mfma_f32_16x16x32_bf16(al[i], bh[j],
                                                            acc[i][j], 0, 0, 0);
        acc[i][j] = __builtin_amdgcn_mfma_f32_16x16x32_bf16(ah[i], bl[j],
                                                            acc[i][j], 0, 0, 0);
      }
  }
#pragma unroll
  for (int i = 0; i < 4; i++) {
#pragma unroll
    for (int r = 0; r < 4; r++) {
      int gm = m0 + wm + i * 16 + fquad * 4 + r;
      if (gm >= Mrows) continue;
      int grow = crow_off + gm;
#pragma unroll
      for (int j = 0; j < 4; j++) {
        int gn = n0 + wn + j * 16 + frow;
        if (gn >= N) continue;
        float v = acc[i][j][r];
        if constexpr (BIAS) v += bias[gn];
        if constexpr (ACT == 1) v = v >= 0.f ? v : 0.2f * v;
        if constexpr (OSPLIT) {
          short h, l;
          split_bf16(v, h, l);
          Oh[(size_t)grow * N + gn] = h;
          Ol[(size_t)grow * N + gn] = l;
        } else {
          Co[(size_t)grow * ldc + gn] = v;
        }
      }
    }
  }
}

// ------------------- split-bf16 MFMA GEMM (MTx64, B-direct) ----------------
// OMODE: 0 fp32 Co (stride ldc), 2 x_proj dual: planes (stride NDP) for
//        gn<32 AND fp32 Co[row*32 + gn-24] for gn>=24 (B/C region).
// ACT: 0 none, 2 fast-softplus, 4 combine v = e2*(e1 + v) (stride ldc).
// MT: m-tile rows (64 default; 16 for thin-N latency-starved GEMMs).
template <int ACT, bool BIAS, int OMODE, int MT = 64>
__global__ __launch_bounds__(256) void mgemm64_k(
    const short* __restrict__ Ah, const short* __restrict__ Al, int lda, int K,
    const short* __restrict__ Wh, const short* __restrict__ Wl, int N,
    const float* __restrict__ bias, float* __restrict__ Co, int ldc,
    short* __restrict__ Oh, short* __restrict__ Ol,
    const float* __restrict__ e1, const float* __restrict__ e2, int Mrows,
    int crow_off) {
  __shared__ __align__(16) short sAh[MT * 32];
  __shared__ __align__(16) short sAl[MT * 32];
  const int tid = threadIdx.x;
  const int wave = tid >> 6, lane = tid & 63;
  const int m0 = blockIdx.y * MT, n0 = blockIdx.x * 64;
  const int schunk = tid & 3;
  const int frow = lane & 15, fquad = lane >> 4;
  const int KST = K >> 5;
  const int nfw = (n0 >> 4) + wave;

  int lm = m0 + ((MT == 64) ? (tid >> 2) : (lane >> 2));
  if (lm >= Mrows) lm = Mrows - 1;
  size_t aoff = (size_t)lm * lda;

  floatx4 acc[MT / 16] = {};
  for (int k0 = 0; k0 < K; k0 += 32) {
    if (k0) __syncthreads();
    const int kc = k0 + schunk * 8;
    if constexpr (MT == 64) {
      GLOAD_LDS16(Ah + aoff + kc, &sAh[(wave * 16) * 32]);
      GLOAD_LDS16(Al + aoff + kc, &sAl[(wave * 16) * 32]);
    } else {
      if (wave == 0) GLOAD_LDS16(Ah + aoff + kc, &sAh[0]);
      if (wave == 1) GLOAD_LDS16(Al + aoff + kc, &sAl[0]);
    }
    const int ks = k0 >> 5;
    short8 bh, bl;
    {
      size_t bo = (((size_t)nfw * KST + ks) * 64 + lane) * 8;
      bh = *(const short8*)&Wh[bo];
      bl = *(const short8*)&Wl[bo];
    }
    __syncthreads();
    short8 ah[MT / 16], al[MT / 16];
#pragma unroll
    for (int i = 0; i < MT / 16; i++) {
      int ra = (i * 16 + frow) * 32 + fquad * 8;
      ah[i] = *(const short8*)&sAh[ra];
      al[i] = *(const short8*)&sAl[ra];
    }
#pragma unroll
    for (int i = 0; i < MT / 16; i++) {
      acc[i] = __builtin_amdgcn_mfma_f32_16x16x32_bf16(ah[i], bh, acc[i], 0, 0, 0);
      acc[i] = __builtin_amdgcn_mfma_f32_16x16x32_bf16(al[i], bh, acc[i], 0, 0, 0);
      acc[i] = __builtin_amdgcn_mfma_f32_16x16x32_bf16(ah[i], bl, acc[i], 0, 0, 0);
    }
  }
  const int gn = n0 + wave * 16 + frow;
  if (gn < N) {
#pragma unroll
    for (int i = 0; i < MT / 16; i++) {
#pragma unroll
      for (int r = 0; r < 4; r++) {
        int gm = m0 + i * 16 + fquad * 4 + r;
        if (gm >= Mrows) continue;
        int grow = crow_off + gm;
        float v = acc[i][r];
        if constexpr (BIAS) v += bias[gn];
        if constexpr (ACT == 2) v = (v > 20.f) ? v : __logf(1.f + __expf(v));
        if constexpr (ACT == 4) {
          size_t o = (size_t)grow * ldc + gn;
          v = e2[o] * (e1[o] + v);
        }
        if constexpr (OMODE == 2) {
          if (gn < NDP) {
            short h, l;
            split_bf16(v, h, l);
            Oh[(size_t)grow * NDP + gn] = h;
            Ol[(size_t)grow * NDP + gn] = l;
          }
          if (gn >= DTR) Co[(size_t)grow * 32 + (gn - DTR)] = v;
        } else {
          Co[(size_t)grow * ldc + gn] = v;
        }
      }
    }
  }
}

// --------------------------- depthwise conv + silu -------------------------
__global__ __launch_bounds__(256) void conv_k(const float* __restrict__ xz,
                                              const float* __restrict__ cw,
                                              const float* __restrict__ cb,
                                              short* __restrict__ xch,
                                              short* __restrict__ xcl) {
  int idx = blockIdx.x * 256 + threadIdx.x;  // [0, HB*NQ*384)
  int dh = idx % (DI / 2);
  int rem = idx / (DI / 2);
  int q = rem % NQ;
  int b = rem / NQ;
  int d = dh * 2;
  int t0 = q * 4;
  const float* base = xz + (size_t)b * T * XZdim + d;
  float4 cwa = *(const float4*)&cw[d * 4];
  float4 cwb = *(const float4*)&cw[(d + 1) * 4];
  float cb0 = cb[d], cb1 = cb[d + 1];
  float2 w[7];
#pragma unroll
  for (int j = 0; j < 7; j++) {
    int tt = t0 - 3 + j;
    w[j] = (tt >= 0 && tt < T) ? *(const float2*)(base + (size_t)tt * XZdim)
                               : make_float2(0.f, 0.f);
  }
  const float cwx[4] = {cwa.x, cwa.y, cwa.z, cwa.w};
  const float cwy[4] = {cwb.x, cwb.y, cwb.z, cwb.w};
#pragma unroll
  for (int r = 0; r < 4; r++) {
    int t = t0 + r;
    if (t >= T) break;
    float a0 = cb0, a1 = cb1;
#pragma unroll
    for (int j = 0; j < 4; j++) {
      a0 += w[r + j].x * cwx[j];
      a1 += w[r + j].y * cwy[j];
    }
    float v0 = a0 / (1.f + __expf(-a0));
    float v1 = a1 / (1.f + __expf(-a1));
    short h0, l0, h1, l1;
    split_bf16(v0, h0, l0);
    split_bf16(v1, h1, l1);
    size_t o = ((size_t)b * T + t) * DI + d;
    *(short2*)&xch[o] = make_short2(h0, h1);
    *(short2*)&xcl[o] = make_short2(l0, l1);
  }
}

// ----------------------- chunked selective scan ----------------------------
// Phase 1: local scan from h=0; stores h_local[16] + sum(dt) per (b,ch,d).
__global__ __launch_bounds__(256) void scan_p1_k(
    const float* __restrict__ xzb, const short* __restrict__ xch,
    const short* __restrict__ xcl, const float* __restrict__ xdbc,
    const float* __restrict__ alog, float* __restrict__ hchk,
    float* __restrict__ sdt) {
  int d = blockIdx.x * 256 + threadIdx.x;
  int ch = blockIdx.y, b = blockIdx.z;
  float A[DSTATE], h[DSTATE];
  bool powA = true;
#pragma unroll
  for (int s = 0; s < DSTATE; s++) {
    A[s] = -expf(alog[d * DSTATE + s]);
    powA = powA && (fabsf(A[s] + (float)(s + 1)) <= 1e-4f * (float)(s + 1));
    h[s] = 0.f;
  }
  const int t0 = ch * TC;
  const float* xzr = xzb + ((size_t)b * T + t0) * XZdim;
  const short* xchr = xch + ((size_t)b * T + t0) * DI;
  const short* xclr = xcl + ((size_t)b * T + t0) * DI;
  const float* bcr = xdbc + ((size_t)b * T + t0) * 32;
  float sd = 0.f;
  if (powA) {
    for (int t = 0; t < TC; t++) {
      float dt = xzr[(size_t)t * XZdim + d];
      float xv = join_bf16(xchr[(size_t)t * DI + d], xclr[(size_t)t * DI + d]);
      float dx = dt * xv;
      const float* bc = bcr + (size_t)t * 32;
      sd += dt;
      float ev[DSTATE];
      pow16(__expf(-dt), ev);
#pragma unroll
      for (int s = 0; s < DSTATE; s++) h[s] = h[s] * ev[s] + dx * bc[s];
    }
  } else {
    for (int t = 0; t < TC; t++) {
      float dt = xzr[(size_t)t * XZdim + d];
      float xv = join_bf16(xchr[(size_t)t * DI + d], xclr[(size_t)t * DI + d]);
      float dx = dt * xv;
      const float* bc = bcr + (size_t)t * 32;
      sd += dt;
#pragma unroll
      for (int s = 0; s < DSTATE; s++)
        h[s] = h[s] * __expf(dt * A[s]) + dx * bc[s];
    }
  }
  size_t o = ((size_t)(b * NCHUNK + ch) * DSTATE) * DI + d;
#pragma unroll
  for (int s = 0; s < DSTATE; s++) hchk[o + (size_t)s * DI] = h[s];
  sdt[(size_t)(b * NCHUNK + ch) * DI + d] = sd;
}

// Phase 2: per (b,s,d), NCHUNK-chunk recurrence; P recomputed from sdt.
__global__ __launch_bounds__(256) void scan_p2_k(float* __restrict__ hchk,
                                                 const float* __restrict__ sdt,
                                                 const float* __restrict__ alog) {
  int idx = blockIdx.x * 256 + threadIdx.x;  // [0, HB*DSTATE*DI)
  int d = idx % DI;
  int rem = idx / DI;
  int s = rem % DSTATE, b = rem / DSTATE;
  float A = -expf(alog[d * DSTATE + s]);
  float hin = 0.f;
#pragma unroll
  for (int ch = 0; ch < NCHUNK; ch++) {
    size_t o = ((size_t)(b * NCHUNK + ch) * DSTATE + s) * DI + d;
    float P = __expf(A * sdt[(size_t)(b * NCHUNK + ch) * DI + d]);
    float hl = hchk[o];
    hchk[o] = hin;
    hin = P * hin + hl;
  }
}

// Phase 3: rescan from incoming state; y = h.C + D*x, gated silu(z) -> planes.
__global__ __launch_bounds__(256) void scan_p3_k(
    const float* __restrict__ xzb, const short* __restrict__ xch,
    const short* __restrict__ xcl, const float* __restrict__ xdbc,
    const float* __restrict__ alog, const float* __restrict__ Dp,
    const float* __restrict__ hchk, short* __restrict__ yh,
    short* __restrict__ yl) {
  int d = blockIdx.x * 256 + threadIdx.x;
  int ch = blockIdx.y, b = blockIdx.z;
  float A[DSTATE], h[DSTATE];
  bool powA = true;
  size_t o = ((size_t)(b * NCHUNK + ch) * DSTATE) * DI + d;
#pragma unroll
  for (int s = 0; s < DSTATE; s++) {
    A[s] = -expf(alog[d * DSTATE + s]);
    powA = powA && (fabsf(A[s] + (float)(s + 1)) <= 1e-4f * (float)(s + 1));
    h[s] = hchk[o + (size_t)s * DI];
  }
  float Dd = Dp[d];
  const int t0 = ch * TC;
  const float* xzr = xzb + ((size_t)b * T + t0) * XZdim;
  const short* xchr = xch + ((size_t)b * T + t0) * DI;
  const short* xclr = xcl + ((size_t)b * T + t0) * DI;
  const float* bcr = xdbc + ((size_t)b * T + t0) * 32;
  if (powA) {
    for (int t = 0; t < TC; t++) {
      float dt = xzr[(size_t)t * XZdim + d];
      float xv = join_bf16(xchr[(size_t)t * DI + d], xclr[(size_t)t * DI + d]);
      float zv = xzr[(size_t)t * XZdim + DI + d];
      float dx = dt * xv;
      float accv = 0.f;
      const float* bc = bcr + (size_t)t * 32;
      float ev[DSTATE];
      pow16(__expf(-dt), ev);
#pragma unroll
      for (int s = 0; s < DSTATE; s++) {
        h[s] = h[s] * ev[s] + dx * bc[s];
        accv += h[s] * bc[DSTATE + s];
      }
      float y = accv + Dd * xv;
      float sz = zv / (1.f + __expf(-zv));
      float v = y * sz;
      short hh, ll;
      split_bf16(v, hh, ll);
      size_t oi = ((size_t)(b * T + t0 + t)) * DI + d;
      yh[oi] = hh;
      yl[oi] = ll;
    }
  } else {
    for (int t = 0; t < TC; t++) {
      float dt = xzr[(size_t)t * XZdim + d];
      float xv = join_bf16(xchr[(size_t)t * DI + d], xclr[(size_t)t * DI + d]);
      float zv = xzr[(size_t)t * XZdim + DI + d];
      float dx = dt * xv;
      float accv = 0.f;
      const float* bc = bcr + (size_t)t * 32;
#pragma unroll
      for (int s = 0; s < DSTATE; s++) {
        h[s] = h[s] * __expf(dt * A[s]) + dx * bc[s];
        accv += h[s] * bc[DSTATE + s];
      }
      float y = accv + Dd * xv;
      float sz = zv / (1.f + __expf(-zv));
      float v = y * sz;
      short hh, ll;
      split_bf16(v, hh, ll);
      size_t oi = ((size_t)(b * T + t0 + t)) * DI + d;
      yh[oi] = hh;
      yl[oi] = ll;
    }
  }
}

// ---------------- final LN + transpose scatter (contiguous writes) ---------
__global__ __launch_bounds__(256) void ln_scatter_k(
    const float* __restrict__ x, const float* __restrict__ stats,
    const float* __restrict__ g, const float* __restrict__ bb,
    float* __restrict__ out) {
  __shared__ float lds[64][129];
  int blk = blockIdx.x, tid = threadIdx.x;
  if (blk < 240) {
    int b = blk / 15, g_ = blk % 15;
    int sec = g_ / 5, s = g_ % 5;
    const int rbase = b * T + g_ * 64;
    for (int cc = 0; cc < 3; cc++) {
      if (cc) __syncthreads();
#pragma unroll
      for (int i = 0; i < 32; i++) {
        int lin = tid + 256 * i;  // [0, 8192)
        int p = lin >> 7, c = lin & 127;
        int row = rbase + p;
        int ccc = cc * 128 + c;
        float v = x[(size_t)row * C + ccc];
        v = (v - stats[2 * row]) * stats[2 * row + 1] * g[ccc] + bb[ccc];
        lds[p][c] = v;
      }
      __syncthreads();
      size_t obase = (size_t)sec * SEC_SZ +
                     (((size_t)(b * 5 + s) * C + cc * 128) << 6);
#pragma unroll
      for (int i = 0; i < 32; i++) {
        int lin = tid + 256 * i;
        int c = lin >> 6, p = lin & 63;
        out[obase + ((size_t)c << 6) + p] = lds[p][c];
      }
    }
  } else {
#pragma unroll
    for (int i = 0; i < 48; i++) {
      int lin = tid + 256 * i;
      int r = lin / C, c = lin % C;
      int b = r >> 1, e = r & 1;
      int row = b * T + NTOK + e;
      float v = x[(size_t)row * C + c];
      v = (v - stats[2 * row]) * stats[2 * row + 1] * g[c] + bb[c];
      out[3 * SEC_SZ + ((size_t)(b * 2 + e)) * C + c] = v;
    }
  }
}

// --------------------------------- launch ----------------------------------
extern "C" void kernel_launch(void* const* d_in, const int* in_sizes, int n_in,
                              void* d_out, int out_size, void* d_ws,
                              size_t ws_size, hipStream_t stream) {
  const float* image = (const float*)d_in[0];
  const float* lidar = (const float*)d_in[1];
  const float* radar = (const float*)d_in[2];
  const float* gps = (const float*)d_in[3];
  const float* pe = (const float*)d_in[4];
  const float* ln1g = (const float*)d_in[5];
  const float* ln1b = (const float*)d_in[6];
  const float* fc1w = (const float*)d_in[7];
  const float* fc1b = (const float*)d_in[8];
  const float* fc2w = (const float*)d_in[9];
  const float* fc2b_ = (const float*)d_in[10];
  const float* inw = (const float*)d_in[11];
  const float* cw = (const float*)d_in[12];
  const float* cb = (const float*)d_in[13];
  const float* xw = (const float*)d_in[14];
  const float* dtw = (const float*)d_in[15];
  const float* dtb = (const float*)d_in[16];
  const float* alog = (const float*)d_in[17];
  const float* Dp = (const float*)d_in[18];
  const float* ow = (const float*)d_in[19];
  const float* lnfg = (const float*)d_in[20];
  const float* lnfb = (const float*)d_in[21];
  float* out = (float*)d_out;

  // ------------- workspace carve-up (56,654,912 floats = 226.6 MB) ---------
  constexpr size_t MC = (size_t)M * C;  // 5,910,528
  float* ws = (float*)d_ws;
  float* x = ws;                            // MC (upper half aliases hchk)
  float* fcb = x + MC;                      // MC (fc2 lrelu result)
  float* bmfm = fcb + MC;                   // MC (ln planes alias; then bm)
  float* x1f = bmfm + MC;                   // MC (x1 planes)
  float* yf = x1f + MC;                     // MC (y planes, half-local)
  float* xz_h = yf + MC;                    // MH*1536
  float* xcp = xz_h + (size_t)MH * XZdim;   // MH*DI floats (xc planes)
  float* xdp = xcp + (size_t)MH * DI;       // MH*64 floats (dt planes + B/C)
  float* wpl = xdp + (size_t)MH * 64;       // weight planes

  // hchk/sdtb alias x upper half: x rows [MH,M) are dead from ln_fused
  // (layer start) until the dir0 combine writes, which happen after each
  // mamba call's scan_p3. CHK_H + sdt = 2,715,648 <= MC/2 = 2,955,264.
  constexpr size_t CHK_H = (size_t)HB * NCHUNK * DSTATE * DI;  // 2,555,904
  static_assert(CHK_H + (size_t)HB * NCHUNK * DI <= MC / 2, "alias overflow");
  float* hchk = x + MC / 2;
  float* sdtb = hchk + CHK_H;

  short* lnh = (short*)bmfm;  // ln planes dead before bm written
  short* lnl = lnh + MC;
  float* bm = bmfm;  // dir1 out_proj result (fp32, full M)
  short* x1h = (short*)x1f;
  short* x1l = x1h + MC;
  short* yh = (short*)yf;
  short* yl = yh + (size_t)MH * DI;
  short* xch = (short*)xcp;
  short* xcl = xch + (size_t)MH * DI;
  short* xdh = (short*)xdp;                  // MH*32 shorts (dt_r hi plane)
  short* xdl = xdh + (size_t)MH * NDP;       // MH*32 shorts (dt_r lo plane)
  float* xdbc = xdp + (size_t)MH * 32;       // MH*32 floats (fp32 B|C)

  short* wf1h = (short*)wpl;
  short* wf1l = wf1h + WSZ1;
  short* wf2h = wf1l + WSZ1;
  short* wf2l = wf2h + WSZ1;
  short* winh = wf2l + WSZ1;
  short* winl = winh + WSZI;
  short* wowh = winl + WSZI;
  short* wowl = wowh + WSZO;
  short* wxh = wowl + WSZO;
  short* wxl = wxh + WSZX;
  short* wdth = wxl + WSZX;
  short* wdtl = wdth + WSZD;
  float* stats2 = (float*)(wdtl + WSZD);     // 2*M floats (final-LN stats)

  // ------------- weight casts to swizzled fragment order (per call) --------
  cast_swz_k<C, C, 12><<<dim3((int)(SET1 / 256), 4), 256, 0, stream>>>(
      fc1w, wf1h, wf1l);
  cast_swz_k<C, C, 12><<<dim3((int)(SET1 / 256), 4), 256, 0, stream>>>(
      fc2w, wf2h, wf2l);
  cast_swz_k<2 * DI, C, 12><<<dim3((int)(SETI / 256), 8), 256, 0, stream>>>(
      inw, winh, winl);
  cast_swz_k<C, DI, 24><<<dim3((int)(SETO / 256), 8), 256, 0, stream>>>(
      ow, wowh, wowl);
  cast_swz_k<ND, DI, 24><<<dim3((int)(SETX / 256), 8), 256, 0, stream>>>(
      xw, wxh, wxl);
  cast_swz_k<DI, DTR, 1><<<dim3((int)(SETD / 256), 8), 256, 0, stream>>>(
      dtw, wdth, wdtl);

  assemble_t_k<<<721, 256, 0, stream>>>(image, lidar, radar, gps, pe, x);

  for (int l = 0; l < NLAYER; l++) {
    ln_fused_k<<<M / 4, 256, 0, stream>>>(x, ln1g + l * C, ln1b + l * C, lnh,
                                          lnl);
    // fc1 = LN(x) @ fc1_w^T + b -> bf16 planes (full M)
    mgemm_k<0, true, false, true, false><<<dim3(3, 121), 256, 0, stream>>>(
        lnh, lnl, C, wf1h + l * SET1, wf1l + l * SET1, C, fc1b + l * C,
        nullptr, 0, x1h, x1l, M, 0, 0);
    // fcb = lrelu(flip(xfc1) @ fc2_w^T + b) -> fp32 (full M)
    mgemm_k<1, true, true, false, false><<<dim3(3, 121), 256, 0, stream>>>(
        x1h, x1l, C, wf2h + l * SET1, wf2l + l * SET1, C, fc2b_ + l * C, fcb,
        C, nullptr, nullptr, M, 0, 0);
    // dir1 (backward) first -> bm; dir0 last fuses combine into x.
    for (int di = 0; di < 2; di++) {
      const int dir = 1 - di;
      size_t wo = (size_t)(l * 2 + dir);
      for (int h = 0; h < 2; h++) {
        const int roff = h * MH;
        // in_proj -> xz_h (dir1 reads time-flipped rows of x1); m-major grid
        if (dir == 0)
          mgemm_k<0, false, false, false, true><<<dim3(61, 12), 256, 0, stream>>>(
              x1h, x1l, C, winh + wo * SETI, winl + wo * SETI, 2 * DI, nullptr,
              xz_h, XZdim, nullptr, nullptr, MH, roff, 0);
        else
          mgemm_k<0, false, true, false, true><<<dim3(61, 12), 256, 0, stream>>>(
              x1h, x1l, C, winh + wo * SETI, winl + wo * SETI, 2 * DI, nullptr,
              xz_h, XZdim, nullptr, nullptr, MH, roff, 0);
        // causal depthwise conv + silu -> xc planes (4-t quad)
        conv_k<<<(HB * NQ * (DI / 2)) / 256, 256, 0, stream>>>(
            xz_h, cw + wo * DI * DCONV, cb + wo * DI, xch, xcl);
        // x_proj -> dt_r planes (stride 32) + fp32 B/C (xdbc); MT=16 tiles
        mgemm64_k<0, false, 2, 16><<<dim3(1, MH / 16), 256, 0, stream>>>(
            xch, xcl, DI, DI, wxh + wo * SETX, wxl + wo * SETX, ND, nullptr,
            xdbc, 0, xdh, xdl, nullptr, nullptr, MH, 0);
        // dt_proj (K padded 24->32, zero weight pad) + fast softplus -> xz dt
        mgemm64_k<2, true, 0><<<dim3(12, 121), 256, 0, stream>>>(
            xdh, xdl, NDP, 32, wdth + wo * SETD, wdtl + wo * SETD, DI,
            dtb + wo * DI, xz_h, XZdim, nullptr, nullptr, nullptr, nullptr,
            MH, 0);
        // chunked selective scan -> y planes
        scan_p1_k<<<dim3(3, NCHUNK, HB), 256, 0, stream>>>(
            xz_h, xch, xcl, xdbc, alog + wo * DI * DSTATE, hchk, sdtb);
        scan_p2_k<<<(HB * DSTATE * DI) / 256, 256, 0, stream>>>(
            hchk, sdtb, alog + wo * DI * DSTATE);
        scan_p3_k<<<dim3(3, NCHUNK, HB), 256, 0, stream>>>(
            xz_h, xch, xcl, xdbc, alog + wo * DI * DSTATE, Dp + wo * DI, hchk,
            yh, yl);
        // out_proj (64^2, 726 blocks): dir1 -> bm; dir0 -> x = bm*(fcb + v)
        if (dir == 1)
          mgemm64_k<0, false, 0><<<dim3(6, 121), 256, 0, stream>>>(
              yh, yl, DI, DI, wowh + wo * SETO, wowl + wo * SETO, C, nullptr,
              bm, C, nullptr, nullptr, nullptr, nullptr, MH, roff);
        else
          mgemm64_k<4, false, 0><<<dim3(6, 121), 256, 0, stream>>>(
              yh, yl, DI, DI, wowh + wo * SETO, wowl + wo * SETO, C, nullptr,
              x, C, nullptr, nullptr, fcb, bm, MH, roff);
      }
    }
  }
  ln_stats2_k<<<M / 4, 256, 0, stream>>>(x, stats2);
  ln_scatter_k<<<241, 256, 0, stream>>>(x, stats2, lnfg, lnfb, out);
}

// Round 5
// 2891.259 us; speedup vs baseline: 1.2015x; 1.0610x over previous
//
#include <hip/hip_runtime.h>
#include <cstdint>
#include <cstddef>

// ---------------------------------------------------------------------------
// MambaFusion. R13 (on R12):
// R12 post-mortem: in_proj mgemm is top real kernel (40.8us, FETCH 80MB vs
// ~14MB ideal, WRITE 46MB id's it). All 732 blocks co-resident -> per-XCD L2
// sees A-tiles from all 61 m-tiles (11.8MB >> 4MB) -> A re-fetched per
// n-sweep. R13: XCD-chunked swizzle (f%8 owns contiguous m-range; per-XCD A
// = 3.1MB fits L2): in_proj (nt=12,mpx=8), fc1/fc2 (nt=3,mpx=16), out_proj
// (nt=6,mpx=16). Padded tiles write-clamped; bijective; bit-identical.
// ---------------------------------------------------------------------------

constexpr int BZv = 16, SEQ = 5, NV = 1;
constexpr int C = 384, DSTATE = 16, DCONV = 4, NLAYER = 4;
constexpr int DI = 768;
constexpr int DTR = 24;
constexpr int NTOK = (NV + 2) * SEQ * 64;  // 960
constexpr int T = NTOK + 2;                // 962
constexpr int M = BZv * T;                 // 15392
constexpr int HB = 8;                      // batches per half
constexpr int MH = HB * T;                 // 7696 rows per half
constexpr int XZdim = 2 * DI;              // 1536
constexpr int ND = DTR + 2 * DSTATE;       // 56
constexpr int NDP = 32;                    // dt_r plane stride
constexpr int NCHUNK = 26, TC = 37;        // 26*37 == 962
constexpr int NQ = 241;                    // ceil(T/4) t-quads
constexpr size_t SEC_SZ = (size_t)BZv * SEQ * C * 64;

// swizzled weight set sizes (elements per (layer[,dir]) set)
constexpr size_t SET1 = (size_t)C * C;        // 147,456 (fc)
constexpr size_t SETI = (size_t)2 * DI * C;   // 589,824 (in_proj)
constexpr size_t SETO = (size_t)C * DI;       // 294,912 (out_proj)
constexpr size_t SETX = (size_t)64 * DI;      // 49,152  (x_proj, N pad 56->64)
constexpr size_t SETD = (size_t)DI * 32;      // 24,576  (dt_proj, K pad 24->32)
constexpr size_t WSZ1 = 4 * SET1;             // 589,824
constexpr size_t WSZI = 8 * SETI;             // 4,718,592
constexpr size_t WSZO = 8 * SETO;             // 2,359,296
constexpr size_t WSZX = 8 * SETX;             // 393,216
constexpr size_t WSZD = 8 * SETD;             // 196,608

typedef __attribute__((ext_vector_type(8))) short short8;
typedef __attribute__((ext_vector_type(4))) float floatx4;

#define GLOAD_LDS16(g, l)                                        \
  __builtin_amdgcn_global_load_lds(                              \
      (const __attribute__((address_space(1))) void*)(g),        \
      (__attribute__((address_space(3))) void*)(l), 16, 0, 0)

__device__ __forceinline__ void split_bf16(float v, short& hi, short& lo) {
  unsigned u = __float_as_uint(v);
  unsigned hib = u & 0xFFFF0000u;      // truncate to bf16
  float r = v - __uint_as_float(hib);  // exact residual
  hi = (short)(hib >> 16);
  lo = (short)(__float_as_uint(r) >> 16);
}

__device__ __forceinline__ float join_bf16(short h, short l) {
  return __uint_as_float((unsigned)(unsigned short)h << 16) +
         __uint_as_float((unsigned)(unsigned short)l << 16);
}

// e[s] = e1^(s+1), 15 muls, ~4 deep.
__device__ __forceinline__ void pow16(float e1, float* e) {
  e[0] = e1;
  e[1] = e1 * e1;
  e[3] = e[1] * e[1];
  e[7] = e[3] * e[3];
  e[15] = e[7] * e[7];
  e[2] = e[1] * e[0];
  e[4] = e[3] * e[0];
  e[5] = e[3] * e[1];
  e[6] = e[5] * e[0];
  e[8] = e[7] * e[0];
  e[9] = e[7] * e[1];
  e[10] = e[9] * e[0];
  e[11] = e[7] * e[3];
  e[12] = e[11] * e[0];
  e[13] = e[11] * e[1];
  e[14] = e[13] * e[0];
}

// ------------------------------ token assembly -----------------------------
__global__ __launch_bounds__(256) void assemble_t_k(
    const float* __restrict__ img, const float* __restrict__ lid,
    const float* __restrict__ rad, const float* __restrict__ gps,
    const float* __restrict__ pe, float* __restrict__ x) {
  __shared__ float lds[64][129];
  int blk = blockIdx.x, tid = threadIdx.x;
  if (blk < 720) {
    int b = blk / 45;
    int rem = blk % 45;
    int g_ = rem / 3, cc = rem % 3;
    int sec = g_ / 5, s = g_ % 5;
    int srow = b * 5 + s;
    int which = (cc + sec) % 3;
    const float* src = (which == 0) ? img : (which == 1 ? lid : rad);
    const float* sp = src + (size_t)srow * (C * 64) + cc * 8192;
#pragma unroll
    for (int i = 0; i < 32; i++) {
      int lin = tid + 256 * i;
      lds[lin & 63][lin >> 6] = sp[lin];
    }
    __syncthreads();
#pragma unroll
    for (int i = 0; i < 32; i++) {
      int lin = tid + 256 * i;
      int p = lin >> 7, c = lin & 127;
      int t = g_ * 64 + p;
      int ccc = cc * 128 + c;
      x[((size_t)b * T + t) * C + ccc] = lds[p][c] + pe[(size_t)t * C + ccc];
    }
  } else {
#pragma unroll
    for (int i = 0; i < 48; i++) {
      int lin = tid + 256 * i;
      int r = lin / C, c = lin % C;
      int b = r >> 1, e = r & 1;
      x[((size_t)b * T + NTOK + e) * C + c] =
          gps[((size_t)b * 2 + e) * C + c] + pe[(size_t)(NTOK + e) * C + c];
    }
  }
}

// -------------------- fused LN (stats + apply -> planes) -------------------
__global__ __launch_bounds__(256) void ln_fused_k(
    const float* __restrict__ x, const float* __restrict__ g,
    const float* __restrict__ b, short* __restrict__ oh,
    short* __restrict__ ol) {
  int row = blockIdx.x * 4 + (threadIdx.x >> 6);
  int lane = threadIdx.x & 63;
  const float* xr = x + (size_t)row * C;
  float v[6];
  float s = 0.f;
#pragma unroll
  for (int j = 0; j < 6; j++) {
    v[j] = xr[lane + 64 * j];
    s += v[j];
  }
#pragma unroll
  for (int o = 32; o > 0; o >>= 1) s += __shfl_xor(s, o, 64);
  float mean = s * (1.f / 384.f);
  float q = 0.f;
#pragma unroll
  for (int j = 0; j < 6; j++) {
    float d = v[j] - mean;
    q += d * d;
  }
#pragma unroll
  for (int o = 32; o > 0; o >>= 1) q += __shfl_xor(q, o, 64);
  float rstd = rsqrtf(q * (1.f / 384.f) + 1e-5f);
#pragma unroll
  for (int j = 0; j < 6; j++) {
    int c = lane + 64 * j;
    float val = (v[j] - mean) * rstd * g[c] + b[c];
    short h, l;
    split_bf16(val, h, l);
    oh[(size_t)row * C + c] = h;
    ol[(size_t)row * C + c] = l;
  }
}

// ------------------------- LN row stats (final LN) -------------------------
__global__ __launch_bounds__(256) void ln_stats2_k(const float* __restrict__ x,
                                                   float* __restrict__ stats) {
  int row = blockIdx.x * 4 + (threadIdx.x >> 6);
  int lane = threadIdx.x & 63;
  const float* xr = x + (size_t)row * C;
  float v[6];
  float s = 0.f;
#pragma unroll
  for (int j = 0; j < 6; j++) {
    v[j] = xr[lane + 64 * j];
    s += v[j];
  }
#pragma unroll
  for (int o = 32; o > 0; o >>= 1) s += __shfl_xor(s, o, 64);
  float mean = s * (1.f / 384.f);
  float q = 0.f;
#pragma unroll
  for (int j = 0; j < 6; j++) {
    float d = v[j] - mean;
    q += d * d;
  }
#pragma unroll
  for (int o = 32; o > 0; o >>= 1) q += __shfl_xor(q, o, 64);
  if (lane == 0) {
    stats[2 * row] = mean;
    stats[2 * row + 1] = rsqrtf(q * (1.f / 384.f) + 1e-5f);
  }
}

// ------------------ weight cast to swizzled fragment order -----------------
// Output layout per set: idx = ((nf*KS + ks)*64 + lane)*8 + e, holding
// W[n = nf*16 + (lane&15)][k = ks*32 + (lane>>4)*8 + e], zero-padded when
// n >= NSRC or k >= KSRC. grid: (NP*KS*32/256, nsets).
template <int NSRC, int KSRC, int KS>
__global__ __launch_bounds__(256) void cast_swz_k(const float* __restrict__ src,
                                                  short* __restrict__ oh,
                                                  short* __restrict__ ol) {
  constexpr int NP = (NSRC + 15) & ~15;
  constexpr size_t SETSZ = (size_t)NP * KS * 32;
  int set = blockIdx.y;
  size_t idx = (size_t)blockIdx.x * 256 + threadIdx.x;
  int e = (int)(idx & 7);
  int lane = (int)((idx >> 3) & 63);
  size_t rest = idx >> 9;
  int ks = (int)(rest % KS);
  int nf = (int)(rest / KS);
  int n = nf * 16 + (lane & 15);
  int k = ks * 32 + ((lane >> 4) << 3) + e;
  float v = 0.f;
  if (n < NSRC && k < KSRC)
    v = src[(size_t)set * NSRC * KSRC + (size_t)n * KSRC + k];
  short h, l;
  split_bf16(v, h, l);
  oh[(size_t)set * SETSZ + idx] = h;
  ol[(size_t)set * SETSZ + idx] = l;
}

// ------------------ split-bf16 MFMA GEMM (128x128, B-direct) ---------------
// ACT: 0 none, 1 lrelu(0.2).
// OSPLIT: write hi/lo planes (stride N). W in swizzled fragment order.
// SWAPXY: m-tiles on blockIdx.x. XSWZ: flat 1-D grid, XCD-chunked decode
// (xcd = f%8 owns m-tiles [xcd*mpx, (xcd+1)*mpx), n fastest within).
template <int ACT, bool BIAS, bool FLIPA, bool OSPLIT, bool SWAPXY, bool XSWZ>
__global__ __launch_bounds__(256) void mgemm_k(
    const short* __restrict__ Ah, const short* __restrict__ Al, int K,
    const short* __restrict__ Wh, const short* __restrict__ Wl, int N,
    const float* __restrict__ bias, float* __restrict__ Co, int ldc,
    short* __restrict__ Oh, short* __restrict__ Ol, int Mrows, int arow_off,
    int crow_off, int nt, int mpx) {
  __shared__ __align__(16) short sAh[128 * 32];
  __shared__ __align__(16) short sAl[128 * 32];
  const int tid = threadIdx.x;
  const int wave = tid >> 6, lane = tid & 63;
  int bm_, bn_;
  if constexpr (XSWZ) {
    const int f = blockIdx.x;
    const int xcd = f & 7, j = f >> 3;
    bn_ = j % nt;
    bm_ = xcd * mpx + j / nt;
  } else {
    bm_ = SWAPXY ? blockIdx.x : blockIdx.y;
    bn_ = SWAPXY ? blockIdx.y : blockIdx.x;
  }
  const int m0 = bm_ * 128, n0 = bn_ * 128;
  const int lrow = lane >> 2, lchunk = lane & 3;
  const int wm = (wave >> 1) * 64, wn = (wave & 1) * 64;
  const int frow = lane & 15, fquad = lane >> 4;
  const int KST = K >> 5;
  const int nfb = (n0 + wn) >> 4;

  size_t arow[2];
#pragma unroll
  for (int p = 0; p < 2; p++) {
    int r = p * 64 + wave * 16 + lrow;
    int lm = m0 + r;
    if (lm >= Mrows) lm = Mrows - 1;
    int g = arow_off + lm;
    if (FLIPA) {
      int bb = g / T;
      int tt = g - bb * T;
      g = bb * T + (T - 1 - tt);
    }
    arow[p] = (size_t)g * K;
  }

  floatx4 acc[4][4] = {};
  for (int k0 = 0; k0 < K; k0 += 32) {
    if (k0) __syncthreads();
    const int kc = k0 + lchunk * 8;
#pragma unroll
    for (int p = 0; p < 2; p++) {
      GLOAD_LDS16(Ah + arow[p] + kc, &sAh[(p * 64 + wave * 16) * 32]);
      GLOAD_LDS16(Al + arow[p] + kc, &sAl[(p * 64 + wave * 16) * 32]);
    }
    const int ks = k0 >> 5;
    short8 bh[4], bl[4];
#pragma unroll
    for (int j = 0; j < 4; j++) {
      size_t bo = (((size_t)(nfb + j) * KST + ks) * 64 + lane) * 8;
      bh[j] = *(const short8*)&Wh[bo];
      bl[j] = *(const short8*)&Wl[bo];
    }
    __syncthreads();
    short8 ah[4], al[4];
#pragma unroll
    for (int i = 0; i < 4; i++) {
      int ra = (wm + i * 16 + frow) * 32 + fquad * 8;
      ah[i] = *(const short8*)&sAh[ra];
      al[i] = *(const short8*)&sAl[ra];
    }
#pragma unroll
    for (int i = 0; i < 4; i++)
#pragma unroll
      for (int j = 0; j < 4; j++) {
        acc[i][j] = __builtin_amdgcn_mfma_f32_16x16x32_bf16(ah[i], bh[j],
                                                            acc[i][j], 0, 0, 0);
        acc[i][j] = __builtin_amdgcn_mfma_f32_16x16x32_bf16(al[i], bh[j],
                                                            acc[i][j], 0, 0, 0);
        acc[i][j] = __builtin_amdgcn_mfma_f32_16x16x32_bf16(ah[i], bl[j],
                                                            acc[i][j], 0, 0, 0);
      }
  }
#pragma unroll
  for (int i = 0; i < 4; i++) {
#pragma unroll
    for (int r = 0; r < 4; r++) {
      int gm = m0 + wm + i * 16 + fquad * 4 + r;
      if (gm >= Mrows) continue;
      int grow = crow_off + gm;
#pragma unroll
      for (int j = 0; j < 4; j++) {
        int gn = n0 + wn + j * 16 + frow;
        if (gn >= N) continue;
        float v = acc[i][j][r];
        if constexpr (BIAS) v += bias[gn];
        if constexpr (ACT == 1) v = v >= 0.f ? v : 0.2f * v;
        if constexpr (OSPLIT) {
          short h, l;
          split_bf16(v, h, l);
          Oh[(size_t)grow * N + gn] = h;
          Ol[(size_t)grow * N + gn] = l;
        } else {
          Co[(size_t)grow * ldc + gn] = v;
        }
      }
    }
  }
}

// ------------------- split-bf16 MFMA GEMM (MTx64, B-direct) ----------------
// OMODE: 0 fp32 Co (stride ldc), 2 x_proj dual: planes (stride NDP) for
//        gn<32 AND fp32 Co[row*32 + gn-24] for gn>=24 (B/C region).
// ACT: 0 none, 2 fast-softplus, 4 combine v = e2*(e1 + v) (stride ldc).
// MT: m-tile rows. XSWZ: flat grid, XCD-chunked decode (see mgemm_k).
template <int ACT, bool BIAS, int OMODE, int MT = 64, bool XSWZ = false>
__global__ __launch_bounds__(256) void mgemm64_k(
    const short* __restrict__ Ah, const short* __restrict__ Al, int lda, int K,
    const short* __restrict__ Wh, const short* __restrict__ Wl, int N,
    const float* __restrict__ bias, float* __restrict__ Co, int ldc,
    short* __restrict__ Oh, short* __restrict__ Ol,
    const float* __restrict__ e1, const float* __restrict__ e2, int Mrows,
    int crow_off, int nt, int mpx) {
  __shared__ __align__(16) short sAh[MT * 32];
  __shared__ __align__(16) short sAl[MT * 32];
  const int tid = threadIdx.x;
  const int wave = tid >> 6, lane = tid & 63;
  int bm_, bn_;
  if constexpr (XSWZ) {
    const int f = blockIdx.x;
    const int xcd = f & 7, j = f >> 3;
    bn_ = j % nt;
    bm_ = xcd * mpx + j / nt;
  } else {
    bm_ = blockIdx.y;
    bn_ = blockIdx.x;
  }
  const int m0 = bm_ * MT, n0 = bn_ * 64;
  const int schunk = tid & 3;
  const int frow = lane & 15, fquad = lane >> 4;
  const int KST = K >> 5;
  const int nfw = (n0 >> 4) + wave;

  int lm = m0 + ((MT == 64) ? (tid >> 2) : (lane >> 2));
  if (lm >= Mrows) lm = Mrows - 1;
  size_t aoff = (size_t)lm * lda;

  floatx4 acc[MT / 16] = {};
  for (int k0 = 0; k0 < K; k0 += 32) {
    if (k0) __syncthreads();
    const int kc = k0 + schunk * 8;
    if constexpr (MT == 64) {
      GLOAD_LDS16(Ah + aoff + kc, &sAh[(wave * 16) * 32]);
      GLOAD_LDS16(Al + aoff + kc, &sAl[(wave * 16) * 32]);
    } else {
      if (wave == 0) GLOAD_LDS16(Ah + aoff + kc, &sAh[0]);
      if (wave == 1) GLOAD_LDS16(Al + aoff + kc, &sAl[0]);
    }
    const int ks = k0 >> 5;
    short8 bh, bl;
    {
      size_t bo = (((size_t)nfw * KST + ks) * 64 + lane) * 8;
      bh = *(const short8*)&Wh[bo];
      bl = *(const short8*)&Wl[bo];
    }
    __syncthreads();
    short8 ah[MT / 16], al[MT / 16];
#pragma unroll
    for (int i = 0; i < MT / 16; i++) {
      int ra = (i * 16 + frow) * 32 + fquad * 8;
      ah[i] = *(const short8*)&sAh[ra];
      al[i] = *(const short8*)&sAl[ra];
    }
#pragma unroll
    for (int i = 0; i < MT / 16; i++) {
      acc[i] = __builtin_amdgcn_mfma_f32_16x16x32_bf16(ah[i], bh, acc[i], 0, 0, 0);
      acc[i] = __builtin_amdgcn_mfma_f32_16x16x32_bf16(al[i], bh, acc[i], 0, 0, 0);
      acc[i] = __builtin_amdgcn_mfma_f32_16x16x32_bf16(ah[i], bl, acc[i], 0, 0, 0);
    }
  }
  const int gn = n0 + wave * 16 + frow;
  if (gn < N) {
#pragma unroll
    for (int i = 0; i < MT / 16; i++) {
#pragma unroll
      for (int r = 0; r < 4; r++) {
        int gm = m0 + i * 16 + fquad * 4 + r;
        if (gm >= Mrows) continue;
        int grow = crow_off + gm;
        float v = acc[i][r];
        if constexpr (BIAS) v += bias[gn];
        if constexpr (ACT == 2) v = (v > 20.f) ? v : __logf(1.f + __expf(v));
        if constexpr (ACT == 4) {
          size_t o = (size_t)grow * ldc + gn;
          v = e2[o] * (e1[o] + v);
        }
        if constexpr (OMODE == 2) {
          if (gn < NDP) {
            short h, l;
            split_bf16(v, h, l);
            Oh[(size_t)grow * NDP + gn] = h;
            Ol[(size_t)grow * NDP + gn] = l;
          }
          if (gn >= DTR) Co[(size_t)grow * 32 + (gn - DTR)] = v;
        } else {
          Co[(size_t)grow * ldc + gn] = v;
        }
      }
    }
  }
}

// --------------------------- depthwise conv + silu -------------------------
__global__ __launch_bounds__(256) void conv_k(const float* __restrict__ xz,
                                              const float* __restrict__ cw,
                                              const float* __restrict__ cb,
                                              short* __restrict__ xch,
                                              short* __restrict__ xcl) {
  int idx = blockIdx.x * 256 + threadIdx.x;  // [0, HB*NQ*384)
  int dh = idx % (DI / 2);
  int rem = idx / (DI / 2);
  int q = rem % NQ;
  int b = rem / NQ;
  int d = dh * 2;
  int t0 = q * 4;
  const float* base = xz + (size_t)b * T * XZdim + d;
  float4 cwa = *(const float4*)&cw[d * 4];
  float4 cwb = *(const float4*)&cw[(d + 1) * 4];
  float cb0 = cb[d], cb1 = cb[d + 1];
  float2 w[7];
#pragma unroll
  for (int j = 0; j < 7; j++) {
    int tt = t0 - 3 + j;
    w[j] = (tt >= 0 && tt < T) ? *(const float2*)(base + (size_t)tt * XZdim)
                               : make_float2(0.f, 0.f);
  }
  const float cwx[4] = {cwa.x, cwa.y, cwa.z, cwa.w};
  const float cwy[4] = {cwb.x, cwb.y, cwb.z, cwb.w};
#pragma unroll
  for (int r = 0; r < 4; r++) {
    int t = t0 + r;
    if (t >= T) break;
    float a0 = cb0, a1 = cb1;
#pragma unroll
    for (int j = 0; j < 4; j++) {
      a0 += w[r + j].x * cwx[j];
      a1 += w[r + j].y * cwy[j];
    }
    float v0 = a0 / (1.f + __expf(-a0));
    float v1 = a1 / (1.f + __expf(-a1));
    short h0, l0, h1, l1;
    split_bf16(v0, h0, l0);
    split_bf16(v1, h1, l1);
    size_t o = ((size_t)b * T + t) * DI + d;
    *(short2*)&xch[o] = make_short2(h0, h1);
    *(short2*)&xcl[o] = make_short2(l0, l1);
  }
}

// ----------------------- chunked selective scan ----------------------------
// Phase 1: local scan from h=0; stores h_local[16] + sum(dt) per (b,ch,d).
__global__ __launch_bounds__(256) void scan_p1_k(
    const float* __restrict__ xzb, const short* __restrict__ xch,
    const short* __restrict__ xcl, const float* __restrict__ xdbc,
    const float* __restrict__ alog, float* __restrict__ hchk,
    float* __restrict__ sdt) {
  int d = blockIdx.x * 256 + threadIdx.x;
  int ch = blockIdx.y, b = blockIdx.z;
  float A[DSTATE], h[DSTATE];
  bool powA = true;
#pragma unroll
  for (int s = 0; s < DSTATE; s++) {
    A[s] = -expf(alog[d * DSTATE + s]);
    powA = powA && (fabsf(A[s] + (float)(s + 1)) <= 1e-4f * (float)(s + 1));
    h[s] = 0.f;
  }
  const int t0 = ch * TC;
  const float* xzr = xzb + ((size_t)b * T + t0) * XZdim;
  const short* xchr = xch + ((size_t)b * T + t0) * DI;
  const short* xclr = xcl + ((size_t)b * T + t0) * DI;
  const float* bcr = xdbc + ((size_t)b * T + t0) * 32;
  float sd = 0.f;
  if (powA) {
    for (int t = 0; t < TC; t++) {
      float dt = xzr[(size_t)t * XZdim + d];
      float xv = join_bf16(xchr[(size_t)t * DI + d], xclr[(size_t)t * DI + d]);
      float dx = dt * xv;
      const float* bc = bcr + (size_t)t * 32;
      sd += dt;
      float ev[DSTATE];
      pow16(__expf(-dt), ev);
#pragma unroll
      for (int s = 0; s < DSTATE; s++) h[s] = h[s] * ev[s] + dx * bc[s];
    }
  } else {
    for (int t = 0; t < TC; t++) {
      float dt = xzr[(size_t)t * XZdim + d];
      float xv = join_bf16(xchr[(size_t)t * DI + d], xclr[(size_t)t * DI + d]);
      float dx = dt * xv;
      const float* bc = bcr + (size_t)t * 32;
      sd += dt;
#pragma unroll
      for (int s = 0; s < DSTATE; s++)
        h[s] = h[s] * __expf(dt * A[s]) + dx * bc[s];
    }
  }
  size_t o = ((size_t)(b * NCHUNK + ch) * DSTATE) * DI + d;
#pragma unroll
  for (int s = 0; s < DSTATE; s++) hchk[o + (size_t)s * DI] = h[s];
  sdt[(size_t)(b * NCHUNK + ch) * DI + d] = sd;
}

// Phase 2: per (b,s,d), NCHUNK-chunk recurrence; P recomputed from sdt.
__global__ __launch_bounds__(256) void scan_p2_k(float* __restrict__ hchk,
                                                 const float* __restrict__ sdt,
                                                 const float* __restrict__ alog) {
  int idx = blockIdx.x * 256 + threadIdx.x;  // [0, HB*DSTATE*DI)
  int d = idx % DI;
  int rem = idx / DI;
  int s = rem % DSTATE, b = rem / DSTATE;
  float A = -expf(alog[d * DSTATE + s]);
  float hin = 0.f;
#pragma unroll
  for (int ch = 0; ch < NCHUNK; ch++) {
    size_t o = ((size_t)(b * NCHUNK + ch) * DSTATE + s) * DI + d;
    float P = __expf(A * sdt[(size_t)(b * NCHUNK + ch) * DI + d]);
    float hl = hchk[o];
    hchk[o] = hin;
    hin = P * hin + hl;
  }
}

// Phase 3: rescan from incoming state; y = h.C + D*x, gated silu(z) -> planes.
__global__ __launch_bounds__(256) void scan_p3_k(
    const float* __restrict__ xzb, const short* __restrict__ xch,
    const short* __restrict__ xcl, const float* __restrict__ xdbc,
    const float* __restrict__ alog, const float* __restrict__ Dp,
    const float* __restrict__ hchk, short* __restrict__ yh,
    short* __restrict__ yl) {
  int d = blockIdx.x * 256 + threadIdx.x;
  int ch = blockIdx.y, b = blockIdx.z;
  float A[DSTATE], h[DSTATE];
  bool powA = true;
  size_t o = ((size_t)(b * NCHUNK + ch) * DSTATE) * DI + d;
#pragma unroll
  for (int s = 0; s < DSTATE; s++) {
    A[s] = -expf(alog[d * DSTATE + s]);
    powA = powA && (fabsf(A[s] + (float)(s + 1)) <= 1e-4f * (float)(s + 1));
    h[s] = hchk[o + (size_t)s * DI];
  }
  float Dd = Dp[d];
  const int t0 = ch * TC;
  const float* xzr = xzb + ((size_t)b * T + t0) * XZdim;
  const short* xchr = xch + ((size_t)b * T + t0) * DI;
  const short* xclr = xcl + ((size_t)b * T + t0) * DI;
  const float* bcr = xdbc + ((size_t)b * T + t0) * 32;
  if (powA) {
    for (int t = 0; t < TC; t++) {
      float dt = xzr[(size_t)t * XZdim + d];
      float xv = join_bf16(xchr[(size_t)t * DI + d], xclr[(size_t)t * DI + d]);
      float zv = xzr[(size_t)t * XZdim + DI + d];
      float dx = dt * xv;
      float accv = 0.f;
      const float* bc = bcr + (size_t)t * 32;
      float ev[DSTATE];
      pow16(__expf(-dt), ev);
#pragma unroll
      for (int s = 0; s < DSTATE; s++) {
        h[s] = h[s] * ev[s] + dx * bc[s];
        accv += h[s] * bc[DSTATE + s];
      }
      float y = accv + Dd * xv;
      float sz = zv / (1.f + __expf(-zv));
      float v = y * sz;
      short hh, ll;
      split_bf16(v, hh, ll);
      size_t oi = ((size_t)(b * T + t0 + t)) * DI + d;
      yh[oi] = hh;
      yl[oi] = ll;
    }
  } else {
    for (int t = 0; t < TC; t++) {
      float dt = xzr[(size_t)t * XZdim + d];
      float xv = join_bf16(xchr[(size_t)t * DI + d], xclr[(size_t)t * DI + d]);
      float zv = xzr[(size_t)t * XZdim + DI + d];
      float dx = dt * xv;
      float accv = 0.f;
      const float* bc = bcr + (size_t)t * 32;
#pragma unroll
      for (int s = 0; s < DSTATE; s++) {
        h[s] = h[s] * __expf(dt * A[s]) + dx * bc[s];
        accv += h[s] * bc[DSTATE + s];
      }
      float y = accv + Dd * xv;
      float sz = zv / (1.f + __expf(-zv));
      float v = y * sz;
      short hh, ll;
      split_bf16(v, hh, ll);
      size_t oi = ((size_t)(b * T + t0 + t)) * DI + d;
      yh[oi] = hh;
      yl[oi] = ll;
    }
  }
}

// ---------------- final LN + transpose scatter (contiguous writes) ---------
__global__ __launch_bounds__(256) void ln_scatter_k(
    const float* __restrict__ x, const float* __restrict__ stats,
    const float* __restrict__ g, const float* __restrict__ bb,
    float* __restrict__ out) {
  __shared__ float lds[64][129];
  int blk = blockIdx.x, tid = threadIdx.x;
  if (blk < 240) {
    int b = blk / 15, g_ = blk % 15;
    int sec = g_ / 5, s = g_ % 5;
    const int rbase = b * T + g_ * 64;
    for (int cc = 0; cc < 3; cc++) {
      if (cc) __syncthreads();
#pragma unroll
      for (int i = 0; i < 32; i++) {
        int lin = tid + 256 * i;  // [0, 8192)
        int p = lin >> 7, c = lin & 127;
        int row = rbase + p;
        int ccc = cc * 128 + c;
        float v = x[(size_t)row * C + ccc];
        v = (v - stats[2 * row]) * stats[2 * row + 1] * g[ccc] + bb[ccc];
        lds[p][c] = v;
      }
      __syncthreads();
      size_t obase = (size_t)sec * SEC_SZ +
                     (((size_t)(b * 5 + s) * C + cc * 128) << 6);
#pragma unroll
      for (int i = 0; i < 32; i++) {
        int lin = tid + 256 * i;
        int c = lin >> 6, p = lin & 63;
        out[obase + ((size_t)c << 6) + p] = lds[p][c];
      }
    }
  } else {
#pragma unroll
    for (int i = 0; i < 48; i++) {
      int lin = tid + 256 * i;
      int r = lin / C, c = lin % C;
      int b = r >> 1, e = r & 1;
      int row = b * T + NTOK + e;
      float v = x[(size_t)row * C + c];
      v = (v - stats[2 * row]) * stats[2 * row + 1] * g[c] + bb[c];
      out[3 * SEC_SZ + ((size_t)(b * 2 + e)) * C + c] = v;
    }
  }
}

// --------------------------------- launch ----------------------------------
extern "C" void kernel_launch(void* const* d_in, const int* in_sizes, int n_in,
                              void* d_out, int out_size, void* d_ws,
                              size_t ws_size, hipStream_t stream) {
  const float* image = (const float*)d_in[0];
  const float* lidar = (const float*)d_in[1];
  const float* radar = (const float*)d_in[2];
  const float* gps = (const float*)d_in[3];
  const float* pe = (const float*)d_in[4];
  const float* ln1g = (const float*)d_in[5];
  const float* ln1b = (const float*)d_in[6];
  const float* fc1w = (const float*)d_in[7];
  const float* fc1b = (const float*)d_in[8];
  const float* fc2w = (const float*)d_in[9];
  const float* fc2b_ = (const float*)d_in[10];
  const float* inw = (const float*)d_in[11];
  const float* cw = (const float*)d_in[12];
  const float* cb = (const float*)d_in[13];
  const float* xw = (const float*)d_in[14];
  const float* dtw = (const float*)d_in[15];
  const float* dtb = (const float*)d_in[16];
  const float* alog = (const float*)d_in[17];
  const float* Dp = (const float*)d_in[18];
  const float* ow = (const float*)d_in[19];
  const float* lnfg = (const float*)d_in[20];
  const float* lnfb = (const float*)d_in[21];
  float* out = (float*)d_out;

  // ------------- workspace carve-up (56,654,912 floats = 226.6 MB) ---------
  constexpr size_t MC = (size_t)M * C;  // 5,910,528
  float* ws = (float*)d_ws;
  float* x = ws;                            // MC (upper half aliases hchk)
  float* fcb = x + MC;                      // MC (fc2 lrelu result)
  float* bmfm = fcb + MC;                   // MC (ln planes alias; then bm)
  float* x1f = bmfm + MC;                   // MC (x1 planes)
  float* yf = x1f + MC;                     // MC (y planes, half-local)
  float* xz_h = yf + MC;                    // MH*1536
  float* xcp = xz_h + (size_t)MH * XZdim;   // MH*DI floats (xc planes)
  float* xdp = xcp + (size_t)MH * DI;       // MH*64 floats (dt planes + B/C)
  float* wpl = xdp + (size_t)MH * 64;       // weight planes

  // hchk/sdtb alias x upper half: x rows [MH,M) are dead from ln_fused
  // (layer start) until the dir0 combine writes, which happen after each
  // mamba call's scan_p3. CHK_H + sdt = 2,715,648 <= MC/2 = 2,955,264.
  constexpr size_t CHK_H = (size_t)HB * NCHUNK * DSTATE * DI;  // 2,555,904
  static_assert(CHK_H + (size_t)HB * NCHUNK * DI <= MC / 2, "alias overflow");
  float* hchk = x + MC / 2;
  float* sdtb = hchk + CHK_H;

  short* lnh = (short*)bmfm;  // ln planes dead before bm written
  short* lnl = lnh + MC;
  float* bm = bmfm;  // dir1 out_proj result (fp32, full M)
  short* x1h = (short*)x1f;
  short* x1l = x1h + MC;
  short* yh = (short*)yf;
  short* yl = yh + (size_t)MH * DI;
  short* xch = (short*)xcp;
  short* xcl = xch + (size_t)MH * DI;
  short* xdh = (short*)xdp;                  // MH*32 shorts (dt_r hi plane)
  short* xdl = xdh + (size_t)MH * NDP;       // MH*32 shorts (dt_r lo plane)
  float* xdbc = xdp + (size_t)MH * 32;       // MH*32 floats (fp32 B|C)

  short* wf1h = (short*)wpl;
  short* wf1l = wf1h + WSZ1;
  short* wf2h = wf1l + WSZ1;
  short* wf2l = wf2h + WSZ1;
  short* winh = wf2l + WSZ1;
  short* winl = winh + WSZI;
  short* wowh = winl + WSZI;
  short* wowl = wowh + WSZO;
  short* wxh = wowl + WSZO;
  short* wxl = wxh + WSZX;
  short* wdth = wxl + WSZX;
  short* wdtl = wdth + WSZD;
  float* stats2 = (float*)(wdtl + WSZD);     // 2*M floats (final-LN stats)

  // ------------- weight casts to swizzled fragment order (per call) --------
  cast_swz_k<C, C, 12><<<dim3((int)(SET1 / 256), 4), 256, 0, stream>>>(
      fc1w, wf1h, wf1l);
  cast_swz_k<C, C, 12><<<dim3((int)(SET1 / 256), 4), 256, 0, stream>>>(
      fc2w, wf2h, wf2l);
  cast_swz_k<2 * DI, C, 12><<<dim3((int)(SETI / 256), 8), 256, 0, stream>>>(
      inw, winh, winl);
  cast_swz_k<C, DI, 24><<<dim3((int)(SETO / 256), 8), 256, 0, stream>>>(
      ow, wowh, wowl);
  cast_swz_k<ND, DI, 24><<<dim3((int)(SETX / 256), 8), 256, 0, stream>>>(
      xw, wxh, wxl);
  cast_swz_k<DI, DTR, 1><<<dim3((int)(SETD / 256), 8), 256, 0, stream>>>(
      dtw, wdth, wdtl);

  assemble_t_k<<<721, 256, 0, stream>>>(image, lidar, radar, gps, pe, x);

  for (int l = 0; l < NLAYER; l++) {
    ln_fused_k<<<M / 4, 256, 0, stream>>>(x, ln1g + l * C, ln1b + l * C, lnh,
                                          lnl);
    // fc1 = LN(x) @ fc1_w^T + b -> bf16 planes (XCD-chunked: nt=3, mpx=16)
    mgemm_k<0, true, false, true, false, true><<<384, 256, 0, stream>>>(
        lnh, lnl, C, wf1h + l * SET1, wf1l + l * SET1, C, fc1b + l * C,
        nullptr, 0, x1h, x1l, M, 0, 0, 3, 16);
    // fcb = lrelu(flip(xfc1) @ fc2_w^T + b) -> fp32 (XCD-chunked)
    mgemm_k<1, true, true, false, false, true><<<384, 256, 0, stream>>>(
        x1h, x1l, C, wf2h + l * SET1, wf2l + l * SET1, C, fc2b_ + l * C, fcb,
        C, nullptr, nullptr, M, 0, 0, 3, 16);
    // dir1 (backward) first -> bm; dir0 last fuses combine into x.
    for (int di = 0; di < 2; di++) {
      const int dir = 1 - di;
      size_t wo = (size_t)(l * 2 + dir);
      for (int h = 0; h < 2; h++) {
        const int roff = h * MH;
        // in_proj -> xz_h (XCD-chunked: nt=12, mpx=8, grid 768)
        if (dir == 0)
          mgemm_k<0, false, false, false, false, true><<<768, 256, 0, stream>>>(
              x1h, x1l, C, winh + wo * SETI, winl + wo * SETI, 2 * DI, nullptr,
              xz_h, XZdim, nullptr, nullptr, MH, roff, 0, 12, 8);
        else
          mgemm_k<0, false, true, false, false, true><<<768, 256, 0, stream>>>(
              x1h, x1l, C, winh + wo * SETI, winl + wo * SETI, 2 * DI, nullptr,
              xz_h, XZdim, nullptr, nullptr, MH, roff, 0, 12, 8);
        // causal depthwise conv + silu -> xc planes (4-t quad)
        conv_k<<<(HB * NQ * (DI / 2)) / 256, 256, 0, stream>>>(
            xz_h, cw + wo * DI * DCONV, cb + wo * DI, xch, xcl);
        // x_proj -> dt_r planes (stride 32) + fp32 B/C (xdbc); MT=16 tiles
        mgemm64_k<0, false, 2, 16><<<dim3(1, MH / 16), 256, 0, stream>>>(
            xch, xcl, DI, DI, wxh + wo * SETX, wxl + wo * SETX, ND, nullptr,
            xdbc, 0, xdh, xdl, nullptr, nullptr, MH, 0, 0, 0);
        // dt_proj (K padded 24->32, zero weight pad) + fast softplus -> xz dt
        mgemm64_k<2, true, 0><<<dim3(12, 121), 256, 0, stream>>>(
            xdh, xdl, NDP, 32, wdth + wo * SETD, wdtl + wo * SETD, DI,
            dtb + wo * DI, xz_h, XZdim, nullptr, nullptr, nullptr, nullptr,
            MH, 0, 0, 0);
        // chunked selective scan -> y planes
        scan_p1_k<<<dim3(3, NCHUNK, HB), 256, 0, stream>>>(
            xz_h, xch, xcl, xdbc, alog + wo * DI * DSTATE, hchk, sdtb);
        scan_p2_k<<<(HB * DSTATE * DI) / 256, 256, 0, stream>>>(
            hchk, sdtb, alog + wo * DI * DSTATE);
        scan_p3_k<<<dim3(3, NCHUNK, HB), 256, 0, stream>>>(
            xz_h, xch, xcl, xdbc, alog + wo * DI * DSTATE, Dp + wo * DI, hchk,
            yh, yl);
        // out_proj (64^2, XCD-chunked: nt=6, mpx=16, grid 768)
        if (dir == 1)
          mgemm64_k<0, false, 0, 64, true><<<768, 256, 0, stream>>>(
              yh, yl, DI, DI, wowh + wo * SETO, wowl + wo * SETO, C, nullptr,
              bm, C, nullptr, nullptr, nullptr, nullptr, MH, roff, 6, 16);
        else
          mgemm64_k<4, false, 0, 64, true><<<768, 256, 0, stream>>>(
              yh, yl, DI, DI, wowh + wo * SETO, wowl + wo * SETO, C, nullptr,
              x, C, nullptr, nullptr, fcb, bm, MH, roff, 6, 16);
      }
    }
  }
  ln_stats2_k<<<M / 4, 256, 0, stream>>>(x, stats2);
  ln_scatter_k<<<241, 256, 0, stream>>>(x, stats2, lnfg, lnfb, out);
}